// Round 5
// baseline (216.185 us; speedup 1.0000x reference)
//
#include <hip/hip_runtime.h>
#include <float.h>

#define Bn 2
#define Nn 8192
#define Rr 2048
#define Kk 16
#define CIN 64
#define CL 16
#define COUT 128
#define K2c 256
#define GT (Bn*Rr)      // 4096 groups
#define FD (CL+CIN)     // 80
#define KC (Kk*FD)      // 1280
#define MG 8            // mlp groups per block (v10: 4->8 halves L2 weight traffic)
#define SPLITK 4        // gemm split-K (v10: 8->4 halves part traffic, keeps 2 blk/CU)
#define CCAP 128        // knn candidate cap; expected count ~53 (v5.1 statistic)

// ---------------- prep: weight transposes / permute + pts4 packing ----------------
__global__ __launch_bounds__(256) void prep_kernel(
    const float* __restrict__ t1_w, const float* __restrict__ t2_w,
    const float* __restrict__ t3_w, const float* __restrict__ conv_w,
    const float* __restrict__ points,
    float* __restrict__ t1t, float* __restrict__ t2t,
    float* __restrict__ t3t, float* __restrict__ wp,
    float4* __restrict__ pts4)
{
  int i = blockIdx.x * 256 + threadIdx.x;
  if (i < K2c*48) { int j = i / 48, k = i - j*48; t1t[k*K2c + j] = t1_w[i]; }
  if (i < K2c*K2c) { int j = i >> 8, k = i & 255; t2t[k*K2c + j] = t2_w[i]; t3t[k*K2c + j] = t3_w[i]; }
  if (i < COUT*KC) {
    int o = i / KC, ck = i - o*KC;
    int c = ck >> 4, k = ck & 15;
    wp[(k*FD + c)*COUT + o] = conv_w[i];
  }
  if (i < Bn*Nn) {
    float x = points[i*3+0], y = points[i*3+1], z = points[i*3+2];
    // numpy order: sq = (x*x + y*y) + z*z, muls materialized then summed
    float sq = __fadd_rn(__fadd_rn(__fmul_rn(x,x), __fmul_rn(y,y)), __fmul_rn(z,z));
    pts4[i] = make_float4(x, y, z, sq);
  }
}

// ---------------- knn v9 (unchanged, harness-verified): streamed points ----------------
__global__ __launch_bounds__(512, 4) void knn_kernel(
    const float4* __restrict__ pts4, const int* __restrict__ rep_idx,
    int* __restrict__ nb_idx, float* __restrict__ p_out,
    float* __restrict__ rep_pos_out)
{
  __shared__ float cbuf[8][512];                 // 16 KB per-thread minima [q][t]
  __shared__ unsigned long long coll[8][CCAP];   // 8 KB candidates
  __shared__ float Lst[8][64];                   // 2 KB per-lane tau stats
  __shared__ float4 qS[8];
  __shared__ float  tauS[8];
  __shared__ int    ccnt[8];

  int t    = threadIdx.x;
  int lane = t & 63;
  int w    = t >> 6;                 // 0..7
  int g0   = blockIdx.x * 8;         // 8 | 2048: block never straddles batches
  int b    = g0 >> 11;
  const float4* pb4 = pts4 + (size_t)b*Nn;

  if (t < 8) {
    int g = g0 + t;
    int r = g & 2047;
    qS[t] = pb4[rep_idx[r]];
    ccnt[t] = 0;
  }
  __syncthreads();

  // queries to SGPRs (uniform across block)
  float qx[8], qy[8], qz[8], qw[8];
  #pragma unroll
  for (int q = 0; q < 8; q++) {
    float4 Q = qS[q];
    qx[q] = __uint_as_float(__builtin_amdgcn_readfirstlane(__float_as_uint(Q.x)));
    qy[q] = __uint_as_float(__builtin_amdgcn_readfirstlane(__float_as_uint(Q.y)));
    qz[q] = __uint_as_float(__builtin_amdgcn_readfirstlane(__float_as_uint(Q.z)));
    qw[q] = __uint_as_float(__builtin_amdgcn_readfirstlane(__float_as_uint(Q.w)));
  }

  // ---- pass 1: per-thread min d2 per query; points streamed 4-at-a-time ----
  float m[8];
  #pragma unroll
  for (int q = 0; q < 8; q++) m[q] = FLT_MAX;
  for (int i0 = 0; i0 < 16; i0 += 4) {
    float4 P0 = pb4[t + 512*(i0+0)];
    float4 P1 = pb4[t + 512*(i0+1)];
    float4 P2 = pb4[t + 512*(i0+2)];
    float4 P3 = pb4[t + 512*(i0+3)];
    #pragma unroll
    for (int q = 0; q < 8; q++) {
      float d0 = __fsub_rn(__fadd_rn(qw[q], P0.w), __fmul_rn(2.0f,
                 __fmaf_rn(qz[q], P0.z, __fmaf_rn(qy[q], P0.y, __fmul_rn(qx[q], P0.x)))));
      float d1 = __fsub_rn(__fadd_rn(qw[q], P1.w), __fmul_rn(2.0f,
                 __fmaf_rn(qz[q], P1.z, __fmaf_rn(qy[q], P1.y, __fmul_rn(qx[q], P1.x)))));
      float d2 = __fsub_rn(__fadd_rn(qw[q], P2.w), __fmul_rn(2.0f,
                 __fmaf_rn(qz[q], P2.z, __fmaf_rn(qy[q], P2.y, __fmul_rn(qx[q], P2.x)))));
      float d3 = __fsub_rn(__fadd_rn(qw[q], P3.w), __fmul_rn(2.0f,
                 __fmaf_rn(qz[q], P3.z, __fmaf_rn(qy[q], P3.y, __fmul_rn(qx[q], P3.x)))));
      m[q] = fminf(fminf(fminf(m[q], d0), fminf(d1, d2)), d3);
    }
  }

  #pragma unroll
  for (int q = 0; q < 8; q++) cbuf[q][t] = m[q];
  __syncthreads();

  // ---- tau: wave w handles query w ----
  {
    // per-lane 3rd-smallest of its 8 thread-minima (bounds 3 real distances)
    float C0 = FLT_MAX, C1 = FLT_MAX, C2 = FLT_MAX;
    #pragma unroll
    for (int j = 0; j < 8; j++) {
      float v = cbuf[w][lane + 64*j];
      float n2 = __builtin_amdgcn_fmed3f(C1, C2, v);
      float n1 = __builtin_amdgcn_fmed3f(C0, C1, v);
      float n0 = fminf(C0, v);
      C0 = n0; C1 = n1; C2 = n2;
    }
    Lst[w][lane] = C2;
  }
  __syncthreads();
  {
    // tau = 6th-smallest L (rank 5, lex (L,lane) unique) -> >=18 pts <= tau
    float L = Lst[w][lane];
    int rk = 0;
    #pragma unroll 8
    for (int i = 0; i < 64; i++) {
      float Li = Lst[w][i];
      rk += (Li < L || (Li == L && i < lane)) ? 1 : 0;
    }
    if (rk == 5) tauS[w] = L;
  }
  __syncthreads();

  float tau[8];
  #pragma unroll
  for (int q = 0; q < 8; q++)
    tau[q] = __uint_as_float(__builtin_amdgcn_readfirstlane(__float_as_uint(tauS[q])));

  // ---- pass 2: re-stream points (L2-hot), predicate + collect ----
  for (int i0 = 0; i0 < 16; i0 += 4) {
    float4 Pb[4];
    Pb[0] = pb4[t + 512*(i0+0)];
    Pb[1] = pb4[t + 512*(i0+1)];
    Pb[2] = pb4[t + 512*(i0+2)];
    Pb[3] = pb4[t + 512*(i0+3)];
    #pragma unroll
    for (int u = 0; u < 4; u++) {
      float4 P = Pb[u];
      int idx = t + 512*(i0+u);
      #pragma unroll
      for (int q = 0; q < 8; q++) {
        float dot = __fmaf_rn(qz[q], P.z, __fmaf_rn(qy[q], P.y, __fmul_rn(qx[q], P.x)));
        float d2  = __fsub_rn(__fadd_rn(qw[q], P.w), __fmul_rn(2.0f, dot));
        if (d2 <= tau[q]) {
          int pos = atomicAdd(&ccnt[q], 1);
          if (pos < CCAP) {
            unsigned f = __float_as_uint(d2);
            unsigned mono = f ^ ((unsigned)((int)f >> 31) | 0x80000000u);
            coll[q][pos] = ((unsigned long long)mono << 32) | (unsigned)idx;
          }
        }
      }
    }
  }
  __syncthreads();

  // ---- extraction: exact rank via broadcast-compare (no serial chains) ----
  int cnt = __builtin_amdgcn_readfirstlane(ccnt[w]);
  if (cnt > CCAP) cnt = CCAP;
  unsigned long long k1 = (lane < cnt)      ? coll[w][lane]      : ~0ull;
  unsigned long long k2 = (lane + 64 < cnt) ? coll[w][lane + 64] : ~0ull;
  int r1 = 0, r2 = 0;
  for (int i = 0; i < cnt; i++) {
    unsigned long long ki = coll[w][i];   // broadcast read
    r1 += (ki < k1) ? 1 : 0;
    r2 += (ki < k2) ? 1 : 0;
  }

  int g = g0 + w;
  float4 Q = qS[w];
  if (lane < cnt && r1 >= 1 && r1 <= 16) {
    int om = (int)(k1 & 0xFFFFFFFFull);
    nb_idx[g*Kk + r1 - 1] = om;
    float4 Pm = pb4[om];
    p_out[(g*Kk + r1 - 1)*3 + 0] = __fsub_rn(Pm.x, Q.x);
    p_out[(g*Kk + r1 - 1)*3 + 1] = __fsub_rn(Pm.y, Q.y);
    p_out[(g*Kk + r1 - 1)*3 + 2] = __fsub_rn(Pm.z, Q.z);
  }
  if (lane + 64 < cnt && r2 >= 1 && r2 <= 16) {
    int om = (int)(k2 & 0xFFFFFFFFull);
    nb_idx[g*Kk + r2 - 1] = om;
    float4 Pm = pb4[om];
    p_out[(g*Kk + r2 - 1)*3 + 0] = __fsub_rn(Pm.x, Q.x);
    p_out[(g*Kk + r2 - 1)*3 + 1] = __fsub_rn(Pm.y, Q.y);
    p_out[(g*Kk + r2 - 1)*3 + 2] = __fsub_rn(Pm.z, Q.z);
  }
  if (lane < 3) rep_pos_out[g*3 + lane] = (lane == 0 ? Q.x : (lane == 1 ? Q.y : Q.z));
}

// ---------------- mlp v10: MG=8 (halved L2 weight traffic), depth-4 prefetch ----------------
// v9 analysis: mlp streams the full 560 KB weight set per block; at MG=4 /
// 1024 blocks that is 573 MB of L2 traffic (~16.6us at the 34.5 TB/s L2
// ceiling) and per-CU load demand ~9x the per-CU L2 share -> weight-BW-bound.
// MG=8 amortizes each weight tile over 8 groups: 287 MB. Per-output FP
// sequence unchanged (same K-partition w + 4i + 16j, same order); only more
// groups share each weight fetch. LDS 43.5 KB -> 3 blk/CU by LDS; grid 512.
__device__ __forceinline__ void fma_g(float4& a, float hv, const float4& wv) {
  a.x = fmaf(hv, wv.x, a.x);
  a.y = fmaf(hv, wv.y, a.y);
  a.z = fmaf(hv, wv.z, a.z);
  a.w = fmaf(hv, wv.w, a.w);
}

__global__ __launch_bounds__(256) void mlp_kernel(
    const float* __restrict__ p,
    const float* __restrict__ t1t, const float* __restrict__ t1_b,
    const float* __restrict__ g1v, const float* __restrict__ b1v,
    const float* __restrict__ t2t, const float* __restrict__ t2_b,
    const float* __restrict__ g2v, const float* __restrict__ b2v,
    const float* __restrict__ t3t, const float* __restrict__ t3_b,
    const float* __restrict__ g3v, const float* __restrict__ b3v,
    float* __restrict__ T_out)
{
  __shared__ float pf[48][MG];       // 1.5 KB
  __shared__ float hA[K2c][MG];      // 8 KB
  __shared__ float red[4*32*66];     // 33.8 KB: red[(w*32 + comp*8 + q)*66 + lane]
  int t = threadIdx.x;
  int w = t >> 6, l = t & 63;
  int g0 = blockIdx.x * MG;
  for (int e = t; e < MG*48; e += 256) {
    int g = e / 48, k = e - g*48;
    pf[k][g] = p[(size_t)(g0+g)*48 + k];
  }
  __syncthreads();

  float4 acc[MG];   // acc[q] = group q over cols 4l..4l+3

#define LDW(WSRC, K) (*(const float4*)&WSRC[(size_t)(K)*K2c + 4*l])

#define KSTAGE(WSRC, KDIM, HBUF, WB, KK, KNEXT)                        \
  {                                                                    \
    float4 wc = WB;                                                    \
    if ((KNEXT) < KDIM) WB = LDW(WSRC, KNEXT);                         \
    float4 ha = *(const float4*)&HBUF[KK][0];                          \
    float4 hb = *(const float4*)&HBUF[KK][4];                          \
    fma_g(acc[0], ha.x, wc); fma_g(acc[1], ha.y, wc);                  \
    fma_g(acc[2], ha.z, wc); fma_g(acc[3], ha.w, wc);                  \
    fma_g(acc[4], hb.x, wc); fma_g(acc[5], hb.y, wc);                  \
    fma_g(acc[6], hb.z, wc); fma_g(acc[7], hb.w, wc);                  \
  }

#define KLOOP(WSRC, KDIM, HBUF)                                        \
  {                                                                    \
    _Pragma("unroll")                                                  \
    for (int q = 0; q < MG; q++) acc[q] = make_float4(0.f,0.f,0.f,0.f);\
    float4 wb0 = LDW(WSRC, w);                                         \
    float4 wb1 = (w + 4  < KDIM) ? LDW(WSRC, w + 4)  : wb0;            \
    float4 wb2 = (w + 8  < KDIM) ? LDW(WSRC, w + 8)  : wb0;            \
    float4 wb3 = (w + 12 < KDIM) ? LDW(WSRC, w + 12) : wb0;            \
    for (int k = w; k < KDIM; k += 16) {                               \
      KSTAGE(WSRC, KDIM, HBUF, wb0, k,      k + 16)                    \
      if (k + 4 < KDIM)  KSTAGE(WSRC, KDIM, HBUF, wb1, k + 4,  k + 20) \
      if (k + 8 < KDIM)  KSTAGE(WSRC, KDIM, HBUF, wb2, k + 8,  k + 24) \
      if (k + 12 < KDIM) KSTAGE(WSRC, KDIM, HBUF, wb3, k + 12, k + 28) \
    }                                                                  \
  }

#define WRITE_RED()                                                    \
  {                                                                    \
    _Pragma("unroll")                                                  \
    for (int q = 0; q < MG; q++) {                                     \
      red[(w*32 + 0*8 + q)*66 + l] = acc[q].x;                         \
      red[(w*32 + 1*8 + q)*66 + l] = acc[q].y;                         \
      red[(w*32 + 2*8 + q)*66 + l] = acc[q].z;                         \
      red[(w*32 + 3*8 + q)*66 + l] = acc[q].w;                         \
    }                                                                  \
  }

#define REDUCE(S)                                                      \
  float S[MG];                                                         \
  {                                                                    \
    int lr = t >> 2, cc = t & 3;                                       \
    _Pragma("unroll")                                                  \
    for (int q = 0; q < MG; q++) S[q] = 0.f;                           \
    _Pragma("unroll")                                                  \
    for (int ww = 0; ww < 4; ww++) {                                   \
      _Pragma("unroll")                                                \
      for (int q = 0; q < MG; q++)                                     \
        S[q] += red[(ww*32 + cc*8 + q)*66 + lr];                       \
    }                                                                  \
  }

  // ===== layer 1 (K=48), relu =====
  KLOOP(t1t, 48, pf)
  WRITE_RED()
  __syncthreads();
  {
    REDUCE(s)
    float bb = t1_b[t], gg = g1v[t], oo = b1v[t];
    float4 v0, v1;
    v0.x = fmaxf(fmaf(s[0] + bb, gg, oo), 0.f);
    v0.y = fmaxf(fmaf(s[1] + bb, gg, oo), 0.f);
    v0.z = fmaxf(fmaf(s[2] + bb, gg, oo), 0.f);
    v0.w = fmaxf(fmaf(s[3] + bb, gg, oo), 0.f);
    v1.x = fmaxf(fmaf(s[4] + bb, gg, oo), 0.f);
    v1.y = fmaxf(fmaf(s[5] + bb, gg, oo), 0.f);
    v1.z = fmaxf(fmaf(s[6] + bb, gg, oo), 0.f);
    v1.w = fmaxf(fmaf(s[7] + bb, gg, oo), 0.f);
    *(float4*)&hA[t][0] = v0;
    *(float4*)&hA[t][4] = v1;
  }
  __syncthreads();

  // ===== layer 2 (K=256), relu =====
  KLOOP(t2t, K2c, hA)
  WRITE_RED()
  __syncthreads();
  {
    REDUCE(s)
    float bb = t2_b[t], gg = g2v[t], oo = b2v[t];
    float4 v0, v1;
    v0.x = fmaxf(fmaf(s[0] + bb, gg, oo), 0.f);
    v0.y = fmaxf(fmaf(s[1] + bb, gg, oo), 0.f);
    v0.z = fmaxf(fmaf(s[2] + bb, gg, oo), 0.f);
    v0.w = fmaxf(fmaf(s[3] + bb, gg, oo), 0.f);
    v1.x = fmaxf(fmaf(s[4] + bb, gg, oo), 0.f);
    v1.y = fmaxf(fmaf(s[5] + bb, gg, oo), 0.f);
    v1.z = fmaxf(fmaf(s[6] + bb, gg, oo), 0.f);
    v1.w = fmaxf(fmaf(s[7] + bb, gg, oo), 0.f);
    *(float4*)&hA[t][0] = v0;
    *(float4*)&hA[t][4] = v1;
  }
  __syncthreads();

  // ===== layer 3 (K=256), no relu, to global =====
  KLOOP(t3t, K2c, hA)
  WRITE_RED()
  __syncthreads();
  {
    REDUCE(s)
    float bb = t3_b[t], gg = g3v[t], oo = b3v[t];
    #pragma unroll
    for (int q = 0; q < MG; q++)
      T_out[(size_t)(g0+q)*K2c + t] = fmaf(s[q] + bb, gg, oo);
  }
#undef KLOOP
#undef KSTAGE
#undef LDW
#undef WRITE_RED
#undef REDUCE
}

// ---------------- tf (fused feat), 4 groups/block ----------------
__global__ __launch_bounds__(256) void tf_kernel(
    const float* __restrict__ T_in, const float* __restrict__ features,
    const float* __restrict__ p, const int* __restrict__ nb_idx,
    const float* __restrict__ lift_w, const float* __restrict__ lift_b,
    const float* __restrict__ bng, const float* __restrict__ bnb,
    float* __restrict__ Tf)
{
  __shared__ float T_s[4*K2c];    // 4 KB
  __shared__ float f_s[4*KC];     // 20 KB
  __shared__ float ps[4*48];      // 768 B
  __shared__ int   idxs[64];      // 256 B
  __shared__ float lw[48], lb2[16], lg[16], lo[16];
  int t = threadIdx.x;
  int g0 = blockIdx.x * 4;
  int b = g0 / Rr;                // 4 | 2048: block never straddles batches
  for (int e = t; e < 4*K2c; e += 256) T_s[e] = T_in[(size_t)g0*K2c + e];
  if (t >= 32 && t < 224) {
    int e = t - 32;               // 192 threads cover ps
    ps[e] = p[(size_t)g0*48 + e];
  }
  if (t < 64) idxs[t] = nb_idx[g0*16 + t];
  if (t >= 64 && t < 112)  lw[t-64]   = lift_w[t-64];
  if (t >= 112 && t < 128) lb2[t-112] = lift_b[t-112];
  if (t >= 224 && t < 240) lg[t-224]  = bng[t-224];
  if (t >= 240)            lo[t-240]  = bnb[t-240];
  __syncthreads();

  // gather neighbor features: 64 rows of 64
  {
    int wv = t >> 6, ln = t & 63;
    for (int row = wv; row < 64; row += 4) {
      int gg = row >> 4, k = row & 15;
      f_s[gg*KC + k*FD + CL + ln] = features[((size_t)b*Nn + idxs[row])*CIN + ln];
    }
  }
  // lifted BN+ReLU: 4*16*16 = 1024 elements
  for (int e = t; e < 1024; e += 256) {
    int gg = e >> 8, rem = e & 255, k = rem >> 4, c = rem & 15;
    float acc = ps[gg*48 + k*3 + 0]*lw[c*3+0] + ps[gg*48 + k*3 + 1]*lw[c*3+1]
              + ps[gg*48 + k*3 + 2]*lw[c*3+2] + lb2[c];
    acc = acc*lg[c] + lo[c];
    f_s[gg*KC + k*FD + c] = fmaxf(acc, 0.f);
  }
  __syncthreads();

  int gg = t >> 6;    // wave per group
  int cl = t & 63;
  for (int ci = cl; ci < FD; ci += 64) {
    float fcol[16];
    #pragma unroll
    for (int j = 0; j < 16; j++) fcol[j] = f_s[gg*KC + j*FD + ci];
    #pragma unroll
    for (int k = 0; k < 16; k++) {
      float acc = 0.f;
      #pragma unroll
      for (int j = 0; j < 16; j++) acc = fmaf(T_s[gg*K2c + k*16 + j], fcol[j], acc);
      Tf[(size_t)(g0+gg)*KC + k*FD + ci] = acc;
    }
  }
}

// ---------------- gemm: out = Tf(4096x1280) @ Wp(1280x128), split-K=4 ----------------
__global__ __launch_bounds__(256) void gemm_kernel(
    const float* __restrict__ A,    // Tf
    const float* __restrict__ Bm,   // Wp
    float* __restrict__ part)       // [SPLITK][GT][COUT]
{
  __shared__ float As[16*36];
  __shared__ float Bs[16*COUT];
  int t = threadIdx.x;
  int m0 = blockIdx.x * 32;
  int ky = blockIdx.y;
  int kbase0 = ky * (KC/SPLITK);    // 320
  float acc[4][4];
  #pragma unroll
  for (int i = 0; i < 4; i++)
    #pragma unroll
    for (int j = 0; j < 4; j++) acc[i][j] = 0.f;
  int tn = t & 31, tm = t >> 5;

  for (int kt = 0; kt < KC/SPLITK; kt += 16) {
    int kb = kbase0 + kt;
    {
      int kcol = t & 15, row = t >> 4;
      As[kcol*36 + row]      = A[(size_t)(m0+row)*KC + kb + kcol];
      As[kcol*36 + row + 16] = A[(size_t)(m0+row+16)*KC + kb + kcol];
    }
    {
      int o = t & 127, kk2 = t >> 7;
      #pragma unroll
      for (int p4 = 0; p4 < 8; p4++) {
        int kk = kk2 + p4*2;
        Bs[kk*COUT + o] = Bm[(size_t)(kb+kk)*COUT + o];
      }
    }
    __syncthreads();
    #pragma unroll
    for (int kk = 0; kk < 16; kk++) {
      float4 a4 = *(const float4*)&As[kk*36 + tm*4];
      float4 b4 = *(const float4*)&Bs[kk*COUT + tn*4];
      float av[4] = {a4.x, a4.y, a4.z, a4.w};
      float bv[4] = {b4.x, b4.y, b4.z, b4.w};
      #pragma unroll
      for (int i = 0; i < 4; i++)
        #pragma unroll
        for (int j = 0; j < 4; j++) acc[i][j] = fmaf(av[i], bv[j], acc[i][j]);
    }
    __syncthreads();
  }
  #pragma unroll
  for (int i = 0; i < 4; i++) {
    float4 v = make_float4(acc[i][0], acc[i][1], acc[i][2], acc[i][3]);
    *(float4*)&part[((size_t)ky*GT + m0 + tm*4 + i)*COUT + tn*4] = v;
  }
}

// ---------------- reduce: out = sum(part[0..SPLITK-1]) + bias ----------------
__global__ __launch_bounds__(256) void reduce_kernel(
    const float* __restrict__ part, const float* __restrict__ conv_b,
    float* __restrict__ outp)
{
  int i = blockIdx.x*256 + threadIdx.x;
  float4 s = ((const float4*)conv_b)[i & 31];
  #pragma unroll
  for (int w = 0; w < SPLITK; w++) {
    float4 v = ((const float4*)(part + (size_t)w*GT*COUT))[i];
    s.x += v.x; s.y += v.y; s.z += v.z; s.w += v.w;
  }
  ((float4*)outp)[i] = s;
}

extern "C" void kernel_launch(void* const* d_in, const int* in_sizes, int n_in,
                              void* d_out, int out_size, void* d_ws, size_t ws_size,
                              hipStream_t stream) {
  const float* points   = (const float*)d_in[0];
  const float* features = (const float*)d_in[1];
  const float* lift_w   = (const float*)d_in[2];
  const float* lift_b   = (const float*)d_in[3];
  const float* bn_lift_g= (const float*)d_in[4];
  const float* bn_lift_b= (const float*)d_in[5];
  const float* t1_w     = (const float*)d_in[6];
  const float* t1_b     = (const float*)d_in[7];
  const float* bn1_g    = (const float*)d_in[8];
  const float* bn1_b    = (const float*)d_in[9];
  const float* t2_w     = (const float*)d_in[10];
  const float* t2_b     = (const float*)d_in[11];
  const float* bn2_g    = (const float*)d_in[12];
  const float* bn2_b    = (const float*)d_in[13];
  const float* t3_w     = (const float*)d_in[14];
  const float* t3_b     = (const float*)d_in[15];
  const float* bn3_g    = (const float*)d_in[16];
  const float* bn3_b    = (const float*)d_in[17];
  const float* conv_w   = (const float*)d_in[18];
  const float* conv_b   = (const float*)d_in[19];
  const int*   rep_idx  = (const int*)d_in[20];

  char* ws = (char*)d_ws;
  int*    nb   = (int*)   (ws + 0);          // 256 KB
  float*  p    = (float*) (ws + 262144);     // 768 KB
  float*  T    = (float*) (ws + 1048576);    // 4 MB
  float*  Tf   = (float*) (ws + 5242880);    // 20 MB
  float*  wp   = (float*) (ws + 26214400);   // 640 KB
  float*  t1t  = (float*) (ws + 26869760);   // 48 KB
  float*  t2t  = (float*) (ws + 26918912);   // 256 KB
  float*  t3t  = (float*) (ws + 27181056);   // 256 KB
  float*  part = (float*) (ws + 33554432);   // 16 MB (SPLITK=4 uses 8 MB)
  float4* pts4 = (float4*)(ws + 52428800);   // 256 KB

  float* rep_pos = (float*)d_out;
  float* outp    = (float*)d_out + (size_t)GT*3;

  prep_kernel<<<640, 256, 0, stream>>>(t1_w, t2_w, t3_w, conv_w, points,
                                       t1t, t2t, t3t, wp, pts4);
  knn_kernel<<<GT/8, 512, 0, stream>>>(pts4, rep_idx, nb, p, rep_pos);
  mlp_kernel<<<GT/MG, 256, 0, stream>>>(p, t1t, t1_b, bn1_g, bn1_b,
                                        t2t, t2_b, bn2_g, bn2_b,
                                        t3t, t3_b, bn3_g, bn3_b, T);
  tf_kernel<<<GT/4, 256, 0, stream>>>(T, features, p, nb,
                                      lift_w, lift_b, bn_lift_g, bn_lift_b, Tf);
  dim3 ggrid(GT/32, SPLITK);
  gemm_kernel<<<ggrid, 256, 0, stream>>>(Tf, wp, part);
  reduce_kernel<<<(GT*COUT/4)/256, 256, 0, stream>>>(part, conv_b, outp);
}

// Round 6
// 207.707 us; speedup vs baseline: 1.0408x; 1.0408x over previous
//
#include <hip/hip_runtime.h>
#include <float.h>

#define Bn 2
#define Nn 8192
#define Rr 2048
#define Kk 16
#define CIN 64
#define CL 16
#define COUT 128
#define K2c 256
#define GT (Bn*Rr)      // 4096 groups
#define FD (CL+CIN)     // 80
#define KC (Kk*FD)      // 1280
#define MG 4            // mlp groups per block (v11: revert 8->4; occupancy/latency-bound)
#define SPLITK 4        // gemm split-K (kept from v10)
#define CCAP 128        // knn candidate cap; expected count ~53 (v5.1 statistic)

// ---------------- prep: weight transposes / permute + pts4 packing ----------------
__global__ __launch_bounds__(256) void prep_kernel(
    const float* __restrict__ t1_w, const float* __restrict__ t2_w,
    const float* __restrict__ t3_w, const float* __restrict__ conv_w,
    const float* __restrict__ points,
    float* __restrict__ t1t, float* __restrict__ t2t,
    float* __restrict__ t3t, float* __restrict__ wp,
    float4* __restrict__ pts4)
{
  int i = blockIdx.x * 256 + threadIdx.x;
  if (i < K2c*48) { int j = i / 48, k = i - j*48; t1t[k*K2c + j] = t1_w[i]; }
  if (i < K2c*K2c) { int j = i >> 8, k = i & 255; t2t[k*K2c + j] = t2_w[i]; t3t[k*K2c + j] = t3_w[i]; }
  if (i < COUT*KC) {
    int o = i / KC, ck = i - o*KC;
    int c = ck >> 4, k = ck & 15;
    wp[(k*FD + c)*COUT + o] = conv_w[i];
  }
  if (i < Bn*Nn) {
    float x = points[i*3+0], y = points[i*3+1], z = points[i*3+2];
    // numpy order: sq = (x*x + y*y) + z*z, muls materialized then summed
    float sq = __fadd_rn(__fadd_rn(__fmul_rn(x,x), __fmul_rn(y,y)), __fmul_rn(z,z));
    pts4[i] = make_float4(x, y, z, sq);
  }
}

// ---------------- knn v9 (unchanged, harness-verified): streamed points ----------------
__global__ __launch_bounds__(512, 4) void knn_kernel(
    const float4* __restrict__ pts4, const int* __restrict__ rep_idx,
    int* __restrict__ nb_idx, float* __restrict__ p_out,
    float* __restrict__ rep_pos_out)
{
  __shared__ float cbuf[8][512];                 // 16 KB per-thread minima [q][t]
  __shared__ unsigned long long coll[8][CCAP];   // 8 KB candidates
  __shared__ float Lst[8][64];                   // 2 KB per-lane tau stats
  __shared__ float4 qS[8];
  __shared__ float  tauS[8];
  __shared__ int    ccnt[8];

  int t    = threadIdx.x;
  int lane = t & 63;
  int w    = t >> 6;                 // 0..7
  int g0   = blockIdx.x * 8;         // 8 | 2048: block never straddles batches
  int b    = g0 >> 11;
  const float4* pb4 = pts4 + (size_t)b*Nn;

  if (t < 8) {
    int g = g0 + t;
    int r = g & 2047;
    qS[t] = pb4[rep_idx[r]];
    ccnt[t] = 0;
  }
  __syncthreads();

  // queries to SGPRs (uniform across block)
  float qx[8], qy[8], qz[8], qw[8];
  #pragma unroll
  for (int q = 0; q < 8; q++) {
    float4 Q = qS[q];
    qx[q] = __uint_as_float(__builtin_amdgcn_readfirstlane(__float_as_uint(Q.x)));
    qy[q] = __uint_as_float(__builtin_amdgcn_readfirstlane(__float_as_uint(Q.y)));
    qz[q] = __uint_as_float(__builtin_amdgcn_readfirstlane(__float_as_uint(Q.z)));
    qw[q] = __uint_as_float(__builtin_amdgcn_readfirstlane(__float_as_uint(Q.w)));
  }

  // ---- pass 1: per-thread min d2 per query; points streamed 4-at-a-time ----
  float m[8];
  #pragma unroll
  for (int q = 0; q < 8; q++) m[q] = FLT_MAX;
  for (int i0 = 0; i0 < 16; i0 += 4) {
    float4 P0 = pb4[t + 512*(i0+0)];
    float4 P1 = pb4[t + 512*(i0+1)];
    float4 P2 = pb4[t + 512*(i0+2)];
    float4 P3 = pb4[t + 512*(i0+3)];
    #pragma unroll
    for (int q = 0; q < 8; q++) {
      float d0 = __fsub_rn(__fadd_rn(qw[q], P0.w), __fmul_rn(2.0f,
                 __fmaf_rn(qz[q], P0.z, __fmaf_rn(qy[q], P0.y, __fmul_rn(qx[q], P0.x)))));
      float d1 = __fsub_rn(__fadd_rn(qw[q], P1.w), __fmul_rn(2.0f,
                 __fmaf_rn(qz[q], P1.z, __fmaf_rn(qy[q], P1.y, __fmul_rn(qx[q], P1.x)))));
      float d2 = __fsub_rn(__fadd_rn(qw[q], P2.w), __fmul_rn(2.0f,
                 __fmaf_rn(qz[q], P2.z, __fmaf_rn(qy[q], P2.y, __fmul_rn(qx[q], P2.x)))));
      float d3 = __fsub_rn(__fadd_rn(qw[q], P3.w), __fmul_rn(2.0f,
                 __fmaf_rn(qz[q], P3.z, __fmaf_rn(qy[q], P3.y, __fmul_rn(qx[q], P3.x)))));
      m[q] = fminf(fminf(fminf(m[q], d0), fminf(d1, d2)), d3);
    }
  }

  #pragma unroll
  for (int q = 0; q < 8; q++) cbuf[q][t] = m[q];
  __syncthreads();

  // ---- tau: wave w handles query w ----
  {
    // per-lane 3rd-smallest of its 8 thread-minima (bounds 3 real distances)
    float C0 = FLT_MAX, C1 = FLT_MAX, C2 = FLT_MAX;
    #pragma unroll
    for (int j = 0; j < 8; j++) {
      float v = cbuf[w][lane + 64*j];
      float n2 = __builtin_amdgcn_fmed3f(C1, C2, v);
      float n1 = __builtin_amdgcn_fmed3f(C0, C1, v);
      float n0 = fminf(C0, v);
      C0 = n0; C1 = n1; C2 = n2;
    }
    Lst[w][lane] = C2;
  }
  __syncthreads();
  {
    // tau = 6th-smallest L (rank 5, lex (L,lane) unique) -> >=18 pts <= tau
    float L = Lst[w][lane];
    int rk = 0;
    #pragma unroll 8
    for (int i = 0; i < 64; i++) {
      float Li = Lst[w][i];
      rk += (Li < L || (Li == L && i < lane)) ? 1 : 0;
    }
    if (rk == 5) tauS[w] = L;
  }
  __syncthreads();

  float tau[8];
  #pragma unroll
  for (int q = 0; q < 8; q++)
    tau[q] = __uint_as_float(__builtin_amdgcn_readfirstlane(__float_as_uint(tauS[q])));

  // ---- pass 2: re-stream points (L2-hot), predicate + collect ----
  for (int i0 = 0; i0 < 16; i0 += 4) {
    float4 Pb[4];
    Pb[0] = pb4[t + 512*(i0+0)];
    Pb[1] = pb4[t + 512*(i0+1)];
    Pb[2] = pb4[t + 512*(i0+2)];
    Pb[3] = pb4[t + 512*(i0+3)];
    #pragma unroll
    for (int u = 0; u < 4; u++) {
      float4 P = Pb[u];
      int idx = t + 512*(i0+u);
      #pragma unroll
      for (int q = 0; q < 8; q++) {
        float dot = __fmaf_rn(qz[q], P.z, __fmaf_rn(qy[q], P.y, __fmul_rn(qx[q], P.x)));
        float d2  = __fsub_rn(__fadd_rn(qw[q], P.w), __fmul_rn(2.0f, dot));
        if (d2 <= tau[q]) {
          int pos = atomicAdd(&ccnt[q], 1);
          if (pos < CCAP) {
            unsigned f = __float_as_uint(d2);
            unsigned mono = f ^ ((unsigned)((int)f >> 31) | 0x80000000u);
            coll[q][pos] = ((unsigned long long)mono << 32) | (unsigned)idx;
          }
        }
      }
    }
  }
  __syncthreads();

  // ---- extraction: exact rank via broadcast-compare (no serial chains) ----
  int cnt = __builtin_amdgcn_readfirstlane(ccnt[w]);
  if (cnt > CCAP) cnt = CCAP;
  unsigned long long k1 = (lane < cnt)      ? coll[w][lane]      : ~0ull;
  unsigned long long k2 = (lane + 64 < cnt) ? coll[w][lane + 64] : ~0ull;
  int r1 = 0, r2 = 0;
  for (int i = 0; i < cnt; i++) {
    unsigned long long ki = coll[w][i];   // broadcast read
    r1 += (ki < k1) ? 1 : 0;
    r2 += (ki < k2) ? 1 : 0;
  }

  int g = g0 + w;
  float4 Q = qS[w];
  if (lane < cnt && r1 >= 1 && r1 <= 16) {
    int om = (int)(k1 & 0xFFFFFFFFull);
    nb_idx[g*Kk + r1 - 1] = om;
    float4 Pm = pb4[om];
    p_out[(g*Kk + r1 - 1)*3 + 0] = __fsub_rn(Pm.x, Q.x);
    p_out[(g*Kk + r1 - 1)*3 + 1] = __fsub_rn(Pm.y, Q.y);
    p_out[(g*Kk + r1 - 1)*3 + 2] = __fsub_rn(Pm.z, Q.z);
  }
  if (lane + 64 < cnt && r2 >= 1 && r2 <= 16) {
    int om = (int)(k2 & 0xFFFFFFFFull);
    nb_idx[g*Kk + r2 - 1] = om;
    float4 Pm = pb4[om];
    p_out[(g*Kk + r2 - 1)*3 + 0] = __fsub_rn(Pm.x, Q.x);
    p_out[(g*Kk + r2 - 1)*3 + 1] = __fsub_rn(Pm.y, Q.y);
    p_out[(g*Kk + r2 - 1)*3 + 2] = __fsub_rn(Pm.z, Q.z);
  }
  if (lane < 3) rep_pos_out[g*3 + lane] = (lane == 0 ? Q.x : (lane == 1 ? Q.y : Q.z));
}

// ---------------- mlp v11: MG=4 (4 blk/CU), depth-8 weight prefetch ----------------
// v10 post-mortem: MG=8 -> grid 512 = 2 blk/CU, occupancy 19.5%, VALUBusy 27%:
// the kernel is LATENCY-bound (weights are L2-resident, FETCH 2.7 MB; the L2-BW
// theory was wrong). v11 reverts to MG=4 (grid 1024 = 4 blk/CU, 16 waves/CU)
// and doubles the weight-prefetch distance to 8 rows (k+32 issued at use of k:
// ~440 VALU-cyc between load and use vs ~190, covering 200-300cy L2 latency).
// KSTAGE order over k is unchanged (strictly increasing k = w+4i) -> per-output
// FP summation order bit-identical to the harness-verified v6 mlp.
__device__ __forceinline__ void fma_g(float4& a, float hv, const float4& wv) {
  a.x = fmaf(hv, wv.x, a.x);
  a.y = fmaf(hv, wv.y, a.y);
  a.z = fmaf(hv, wv.z, a.z);
  a.w = fmaf(hv, wv.w, a.w);
}

__global__ __launch_bounds__(256) void mlp_kernel(
    const float* __restrict__ p,
    const float* __restrict__ t1t, const float* __restrict__ t1_b,
    const float* __restrict__ g1v, const float* __restrict__ b1v,
    const float* __restrict__ t2t, const float* __restrict__ t2_b,
    const float* __restrict__ g2v, const float* __restrict__ b2v,
    const float* __restrict__ t3t, const float* __restrict__ t3_b,
    const float* __restrict__ g3v, const float* __restrict__ b3v,
    float* __restrict__ T_out)
{
  __shared__ float pf[48][MG];       // 768 B
  __shared__ float hA[K2c][MG];      // 4 KB
  __shared__ float red[4*16*66];     // 16.9 KB: red[(w*16 + comp*4 + q)*66 + lane]
  int t = threadIdx.x;
  int w = t >> 6, l = t & 63;
  int g0 = blockIdx.x * MG;
  for (int e = t; e < MG*48; e += 256) {
    int g = e / 48, k = e - g*48;
    pf[k][g] = p[(size_t)(g0+g)*48 + k];
  }
  __syncthreads();

  float4 acc[MG];   // acc[q] = group q over cols 4l..4l+3

#define LDW(WSRC, K) (*(const float4*)&WSRC[(size_t)(K)*K2c + 4*l])

#define KSTAGE(WSRC, KDIM, HBUF, WB, KK, KNEXT)                        \
  {                                                                    \
    float4 wc = WB;                                                    \
    if ((KNEXT) < KDIM) WB = LDW(WSRC, KNEXT);                         \
    float4 h = *(const float4*)&HBUF[KK][0];                           \
    fma_g(acc[0], h.x, wc); fma_g(acc[1], h.y, wc);                    \
    fma_g(acc[2], h.z, wc); fma_g(acc[3], h.w, wc);                    \
  }

#define KLOOP(WSRC, KDIM, HBUF)                                        \
  {                                                                    \
    _Pragma("unroll")                                                  \
    for (int q = 0; q < MG; q++) acc[q] = make_float4(0.f,0.f,0.f,0.f);\
    float4 wb0 = LDW(WSRC, w);                                         \
    float4 wb1 = (w + 4  < KDIM) ? LDW(WSRC, w + 4)  : wb0;            \
    float4 wb2 = (w + 8  < KDIM) ? LDW(WSRC, w + 8)  : wb0;            \
    float4 wb3 = (w + 12 < KDIM) ? LDW(WSRC, w + 12) : wb0;            \
    float4 wb4 = (w + 16 < KDIM) ? LDW(WSRC, w + 16) : wb0;            \
    float4 wb5 = (w + 20 < KDIM) ? LDW(WSRC, w + 20) : wb0;            \
    float4 wb6 = (w + 24 < KDIM) ? LDW(WSRC, w + 24) : wb0;            \
    float4 wb7 = (w + 28 < KDIM) ? LDW(WSRC, w + 28) : wb0;            \
    for (int k = w; k < KDIM; k += 32) {                               \
      KSTAGE(WSRC, KDIM, HBUF, wb0, k,      k + 32)                    \
      if (k + 4 < KDIM)  KSTAGE(WSRC, KDIM, HBUF, wb1, k + 4,  k + 36) \
      if (k + 8 < KDIM)  KSTAGE(WSRC, KDIM, HBUF, wb2, k + 8,  k + 40) \
      if (k + 12 < KDIM) KSTAGE(WSRC, KDIM, HBUF, wb3, k + 12, k + 44) \
      if (k + 16 < KDIM) KSTAGE(WSRC, KDIM, HBUF, wb4, k + 16, k + 48) \
      if (k + 20 < KDIM) KSTAGE(WSRC, KDIM, HBUF, wb5, k + 20, k + 52) \
      if (k + 24 < KDIM) KSTAGE(WSRC, KDIM, HBUF, wb6, k + 24, k + 56) \
      if (k + 28 < KDIM) KSTAGE(WSRC, KDIM, HBUF, wb7, k + 28, k + 60) \
    }                                                                  \
  }

#define WRITE_RED()                                                    \
  {                                                                    \
    _Pragma("unroll")                                                  \
    for (int q = 0; q < MG; q++) {                                     \
      red[(w*16 + 0*4 + q)*66 + l] = acc[q].x;                         \
      red[(w*16 + 1*4 + q)*66 + l] = acc[q].y;                         \
      red[(w*16 + 2*4 + q)*66 + l] = acc[q].z;                         \
      red[(w*16 + 3*4 + q)*66 + l] = acc[q].w;                         \
    }                                                                  \
  }

#define REDUCE(S)                                                      \
  float4 S = make_float4(0.f,0.f,0.f,0.f);                             \
  {                                                                    \
    int lr = t >> 2, cc = t & 3;                                       \
    _Pragma("unroll")                                                  \
    for (int ww = 0; ww < 4; ww++) {                                   \
      S.x += red[(ww*16 + cc*4 + 0)*66 + lr];                          \
      S.y += red[(ww*16 + cc*4 + 1)*66 + lr];                          \
      S.z += red[(ww*16 + cc*4 + 2)*66 + lr];                          \
      S.w += red[(ww*16 + cc*4 + 3)*66 + lr];                          \
    }                                                                  \
  }

  // ===== layer 1 (K=48), relu =====
  KLOOP(t1t, 48, pf)
  WRITE_RED()
  __syncthreads();
  {
    REDUCE(s)
    float bb = t1_b[t], gg = g1v[t], oo = b1v[t];
    float4 v;
    v.x = fmaxf(fmaf(s.x + bb, gg, oo), 0.f);
    v.y = fmaxf(fmaf(s.y + bb, gg, oo), 0.f);
    v.z = fmaxf(fmaf(s.z + bb, gg, oo), 0.f);
    v.w = fmaxf(fmaf(s.w + bb, gg, oo), 0.f);
    *(float4*)&hA[t][0] = v;
  }
  __syncthreads();

  // ===== layer 2 (K=256), relu =====
  KLOOP(t2t, K2c, hA)
  WRITE_RED()
  __syncthreads();
  {
    REDUCE(s)
    float bb = t2_b[t], gg = g2v[t], oo = b2v[t];
    float4 v;
    v.x = fmaxf(fmaf(s.x + bb, gg, oo), 0.f);
    v.y = fmaxf(fmaf(s.y + bb, gg, oo), 0.f);
    v.z = fmaxf(fmaf(s.z + bb, gg, oo), 0.f);
    v.w = fmaxf(fmaf(s.w + bb, gg, oo), 0.f);
    *(float4*)&hA[t][0] = v;
  }
  __syncthreads();

  // ===== layer 3 (K=256), no relu, to global =====
  KLOOP(t3t, K2c, hA)
  WRITE_RED()
  __syncthreads();
  {
    REDUCE(s)
    float bb = t3_b[t], gg = g3v[t], oo = b3v[t];
    T_out[(size_t)(g0+0)*K2c + t] = fmaf(s.x + bb, gg, oo);
    T_out[(size_t)(g0+1)*K2c + t] = fmaf(s.y + bb, gg, oo);
    T_out[(size_t)(g0+2)*K2c + t] = fmaf(s.z + bb, gg, oo);
    T_out[(size_t)(g0+3)*K2c + t] = fmaf(s.w + bb, gg, oo);
  }
#undef KLOOP
#undef KSTAGE
#undef LDW
#undef WRITE_RED
#undef REDUCE
}

// ---------------- tf (fused feat), 4 groups/block ----------------
__global__ __launch_bounds__(256) void tf_kernel(
    const float* __restrict__ T_in, const float* __restrict__ features,
    const float* __restrict__ p, const int* __restrict__ nb_idx,
    const float* __restrict__ lift_w, const float* __restrict__ lift_b,
    const float* __restrict__ bng, const float* __restrict__ bnb,
    float* __restrict__ Tf)
{
  __shared__ float T_s[4*K2c];    // 4 KB
  __shared__ float f_s[4*KC];     // 20 KB
  __shared__ float ps[4*48];      // 768 B
  __shared__ int   idxs[64];      // 256 B
  __shared__ float lw[48], lb2[16], lg[16], lo[16];
  int t = threadIdx.x;
  int g0 = blockIdx.x * 4;
  int b = g0 / Rr;                // 4 | 2048: block never straddles batches
  for (int e = t; e < 4*K2c; e += 256) T_s[e] = T_in[(size_t)g0*K2c + e];
  if (t >= 32 && t < 224) {
    int e = t - 32;               // 192 threads cover ps
    ps[e] = p[(size_t)g0*48 + e];
  }
  if (t < 64) idxs[t] = nb_idx[g0*16 + t];
  if (t >= 64 && t < 112)  lw[t-64]   = lift_w[t-64];
  if (t >= 112 && t < 128) lb2[t-112] = lift_b[t-112];
  if (t >= 224 && t < 240) lg[t-224]  = bng[t-224];
  if (t >= 240)            lo[t-240]  = bnb[t-240];
  __syncthreads();

  // gather neighbor features: 64 rows of 64
  {
    int wv = t >> 6, ln = t & 63;
    for (int row = wv; row < 64; row += 4) {
      int gg = row >> 4, k = row & 15;
      f_s[gg*KC + k*FD + CL + ln] = features[((size_t)b*Nn + idxs[row])*CIN + ln];
    }
  }
  // lifted BN+ReLU: 4*16*16 = 1024 elements
  for (int e = t; e < 1024; e += 256) {
    int gg = e >> 8, rem = e & 255, k = rem >> 4, c = rem & 15;
    float acc = ps[gg*48 + k*3 + 0]*lw[c*3+0] + ps[gg*48 + k*3 + 1]*lw[c*3+1]
              + ps[gg*48 + k*3 + 2]*lw[c*3+2] + lb2[c];
    acc = acc*lg[c] + lo[c];
    f_s[gg*KC + k*FD + c] = fmaxf(acc, 0.f);
  }
  __syncthreads();

  int gg = t >> 6;    // wave per group
  int cl = t & 63;
  for (int ci = cl; ci < FD; ci += 64) {
    float fcol[16];
    #pragma unroll
    for (int j = 0; j < 16; j++) fcol[j] = f_s[gg*KC + j*FD + ci];
    #pragma unroll
    for (int k = 0; k < 16; k++) {
      float acc = 0.f;
      #pragma unroll
      for (int j = 0; j < 16; j++) acc = fmaf(T_s[gg*K2c + k*16 + j], fcol[j], acc);
      Tf[(size_t)(g0+gg)*KC + k*FD + ci] = acc;
    }
  }
}

// ---------------- gemm: out = Tf(4096x1280) @ Wp(1280x128), split-K=4 ----------------
__global__ __launch_bounds__(256) void gemm_kernel(
    const float* __restrict__ A,    // Tf
    const float* __restrict__ Bm,   // Wp
    float* __restrict__ part)       // [SPLITK][GT][COUT]
{
  __shared__ float As[16*36];
  __shared__ float Bs[16*COUT];
  int t = threadIdx.x;
  int m0 = blockIdx.x * 32;
  int ky = blockIdx.y;
  int kbase0 = ky * (KC/SPLITK);    // 320
  float acc[4][4];
  #pragma unroll
  for (int i = 0; i < 4; i++)
    #pragma unroll
    for (int j = 0; j < 4; j++) acc[i][j] = 0.f;
  int tn = t & 31, tm = t >> 5;

  for (int kt = 0; kt < KC/SPLITK; kt += 16) {
    int kb = kbase0 + kt;
    {
      int kcol = t & 15, row = t >> 4;
      As[kcol*36 + row]      = A[(size_t)(m0+row)*KC + kb + kcol];
      As[kcol*36 + row + 16] = A[(size_t)(m0+row+16)*KC + kb + kcol];
    }
    {
      int o = t & 127, kk2 = t >> 7;
      #pragma unroll
      for (int p4 = 0; p4 < 8; p4++) {
        int kk = kk2 + p4*2;
        Bs[kk*COUT + o] = Bm[(size_t)(kb+kk)*COUT + o];
      }
    }
    __syncthreads();
    #pragma unroll
    for (int kk = 0; kk < 16; kk++) {
      float4 a4 = *(const float4*)&As[kk*36 + tm*4];
      float4 b4 = *(const float4*)&Bs[kk*COUT + tn*4];
      float av[4] = {a4.x, a4.y, a4.z, a4.w};
      float bv[4] = {b4.x, b4.y, b4.z, b4.w};
      #pragma unroll
      for (int i = 0; i < 4; i++)
        #pragma unroll
        for (int j = 0; j < 4; j++) acc[i][j] = fmaf(av[i], bv[j], acc[i][j]);
    }
    __syncthreads();
  }
  #pragma unroll
  for (int i = 0; i < 4; i++) {
    float4 v = make_float4(acc[i][0], acc[i][1], acc[i][2], acc[i][3]);
    *(float4*)&part[((size_t)ky*GT + m0 + tm*4 + i)*COUT + tn*4] = v;
  }
}

// ---------------- reduce: out = sum(part[0..SPLITK-1]) + bias ----------------
__global__ __launch_bounds__(256) void reduce_kernel(
    const float* __restrict__ part, const float* __restrict__ conv_b,
    float* __restrict__ outp)
{
  int i = blockIdx.x*256 + threadIdx.x;
  float4 s = ((const float4*)conv_b)[i & 31];
  #pragma unroll
  for (int w = 0; w < SPLITK; w++) {
    float4 v = ((const float4*)(part + (size_t)w*GT*COUT))[i];
    s.x += v.x; s.y += v.y; s.z += v.z; s.w += v.w;
  }
  ((float4*)outp)[i] = s;
}

extern "C" void kernel_launch(void* const* d_in, const int* in_sizes, int n_in,
                              void* d_out, int out_size, void* d_ws, size_t ws_size,
                              hipStream_t stream) {
  const float* points   = (const float*)d_in[0];
  const float* features = (const float*)d_in[1];
  const float* lift_w   = (const float*)d_in[2];
  const float* lift_b   = (const float*)d_in[3];
  const float* bn_lift_g= (const float*)d_in[4];
  const float* bn_lift_b= (const float*)d_in[5];
  const float* t1_w     = (const float*)d_in[6];
  const float* t1_b     = (const float*)d_in[7];
  const float* bn1_g    = (const float*)d_in[8];
  const float* bn1_b    = (const float*)d_in[9];
  const float* t2_w     = (const float*)d_in[10];
  const float* t2_b     = (const float*)d_in[11];
  const float* bn2_g    = (const float*)d_in[12];
  const float* bn2_b    = (const float*)d_in[13];
  const float* t3_w     = (const float*)d_in[14];
  const float* t3_b     = (const float*)d_in[15];
  const float* bn3_g    = (const float*)d_in[16];
  const float* bn3_b    = (const float*)d_in[17];
  const float* conv_w   = (const float*)d_in[18];
  const float* conv_b   = (const float*)d_in[19];
  const int*   rep_idx  = (const int*)d_in[20];

  char* ws = (char*)d_ws;
  int*    nb   = (int*)   (ws + 0);          // 256 KB
  float*  p    = (float*) (ws + 262144);     // 768 KB
  float*  T    = (float*) (ws + 1048576);    // 4 MB
  float*  Tf   = (float*) (ws + 5242880);    // 20 MB
  float*  wp   = (float*) (ws + 26214400);   // 640 KB
  float*  t1t  = (float*) (ws + 26869760);   // 48 KB
  float*  t2t  = (float*) (ws + 26918912);   // 256 KB
  float*  t3t  = (float*) (ws + 27181056);   // 256 KB
  float*  part = (float*) (ws + 33554432);   // 16 MB (SPLITK=4 uses 8 MB)
  float4* pts4 = (float4*)(ws + 52428800);   // 256 KB

  float* rep_pos = (float*)d_out;
  float* outp    = (float*)d_out + (size_t)GT*3;

  prep_kernel<<<640, 256, 0, stream>>>(t1_w, t2_w, t3_w, conv_w, points,
                                       t1t, t2t, t3t, wp, pts4);
  knn_kernel<<<GT/8, 512, 0, stream>>>(pts4, rep_idx, nb, p, rep_pos);
  mlp_kernel<<<GT/MG, 256, 0, stream>>>(p, t1t, t1_b, bn1_g, bn1_b,
                                        t2t, t2_b, bn2_g, bn2_b,
                                        t3t, t3_b, bn3_g, bn3_b, T);
  tf_kernel<<<GT/4, 256, 0, stream>>>(T, features, p, nb,
                                      lift_w, lift_b, bn_lift_g, bn_lift_b, Tf);
  dim3 ggrid(GT/32, SPLITK);
  gemm_kernel<<<ggrid, 256, 0, stream>>>(Tf, wp, part);
  reduce_kernel<<<(GT*COUT/4)/256, 256, 0, stream>>>(part, conv_b, outp);
}

// Round 7
// 201.596 us; speedup vs baseline: 1.0724x; 1.0303x over previous
//
#include <hip/hip_runtime.h>
#include <float.h>

#define Bn 2
#define Nn 8192
#define Rr 2048
#define Kk 16
#define CIN 64
#define CL 16
#define COUT 128
#define K2c 256
#define GT (Bn*Rr)      // 4096 groups
#define FD (CL+CIN)     // 80
#define KC (Kk*FD)      // 1280
#define MGB 8           // mlp groups per block (v12: 8 groups, 8 waves, 512 thr)
#define SPLITK 4        // gemm split-K
#define CCAP 128        // knn candidate cap; expected count ~53 (v5.1 statistic)

// ---------------- prep: weight transposes / permute + pts4 packing ----------------
__global__ __launch_bounds__(256) void prep_kernel(
    const float* __restrict__ t1_w, const float* __restrict__ t2_w,
    const float* __restrict__ t3_w, const float* __restrict__ conv_w,
    const float* __restrict__ points,
    float* __restrict__ t1t, float* __restrict__ t2t,
    float* __restrict__ t3t, float* __restrict__ wp,
    float4* __restrict__ pts4)
{
  int i = blockIdx.x * 256 + threadIdx.x;
  if (i < K2c*48) { int j = i / 48, k = i - j*48; t1t[k*K2c + j] = t1_w[i]; }
  if (i < K2c*K2c) { int j = i >> 8, k = i & 255; t2t[k*K2c + j] = t2_w[i]; t3t[k*K2c + j] = t3_w[i]; }
  if (i < COUT*KC) {
    int o = i / KC, ck = i - o*KC;
    int c = ck >> 4, k = ck & 15;
    wp[(k*FD + c)*COUT + o] = conv_w[i];
  }
  if (i < Bn*Nn) {
    float x = points[i*3+0], y = points[i*3+1], z = points[i*3+2];
    // numpy order: sq = (x*x + y*y) + z*z, muls materialized then summed
    float sq = __fadd_rn(__fadd_rn(__fmul_rn(x,x), __fmul_rn(y,y)), __fmul_rn(z,z));
    pts4[i] = make_float4(x, y, z, sq);
  }
}

// ---------------- knn v9 (unchanged, harness-verified): streamed points ----------------
__global__ __launch_bounds__(512, 4) void knn_kernel(
    const float4* __restrict__ pts4, const int* __restrict__ rep_idx,
    int* __restrict__ nb_idx, float* __restrict__ p_out,
    float* __restrict__ rep_pos_out)
{
  __shared__ float cbuf[8][512];                 // 16 KB per-thread minima [q][t]
  __shared__ unsigned long long coll[8][CCAP];   // 8 KB candidates
  __shared__ float Lst[8][64];                   // 2 KB per-lane tau stats
  __shared__ float4 qS[8];
  __shared__ float  tauS[8];
  __shared__ int    ccnt[8];

  int t    = threadIdx.x;
  int lane = t & 63;
  int w    = t >> 6;                 // 0..7
  int g0   = blockIdx.x * 8;         // 8 | 2048: block never straddles batches
  int b    = g0 >> 11;
  const float4* pb4 = pts4 + (size_t)b*Nn;

  if (t < 8) {
    int g = g0 + t;
    int r = g & 2047;
    qS[t] = pb4[rep_idx[r]];
    ccnt[t] = 0;
  }
  __syncthreads();

  // queries to SGPRs (uniform across block)
  float qx[8], qy[8], qz[8], qw[8];
  #pragma unroll
  for (int q = 0; q < 8; q++) {
    float4 Q = qS[q];
    qx[q] = __uint_as_float(__builtin_amdgcn_readfirstlane(__float_as_uint(Q.x)));
    qy[q] = __uint_as_float(__builtin_amdgcn_readfirstlane(__float_as_uint(Q.y)));
    qz[q] = __uint_as_float(__builtin_amdgcn_readfirstlane(__float_as_uint(Q.z)));
    qw[q] = __uint_as_float(__builtin_amdgcn_readfirstlane(__float_as_uint(Q.w)));
  }

  // ---- pass 1: per-thread min d2 per query; points streamed 4-at-a-time ----
  float m[8];
  #pragma unroll
  for (int q = 0; q < 8; q++) m[q] = FLT_MAX;
  for (int i0 = 0; i0 < 16; i0 += 4) {
    float4 P0 = pb4[t + 512*(i0+0)];
    float4 P1 = pb4[t + 512*(i0+1)];
    float4 P2 = pb4[t + 512*(i0+2)];
    float4 P3 = pb4[t + 512*(i0+3)];
    #pragma unroll
    for (int q = 0; q < 8; q++) {
      float d0 = __fsub_rn(__fadd_rn(qw[q], P0.w), __fmul_rn(2.0f,
                 __fmaf_rn(qz[q], P0.z, __fmaf_rn(qy[q], P0.y, __fmul_rn(qx[q], P0.x)))));
      float d1 = __fsub_rn(__fadd_rn(qw[q], P1.w), __fmul_rn(2.0f,
                 __fmaf_rn(qz[q], P1.z, __fmaf_rn(qy[q], P1.y, __fmul_rn(qx[q], P1.x)))));
      float d2 = __fsub_rn(__fadd_rn(qw[q], P2.w), __fmul_rn(2.0f,
                 __fmaf_rn(qz[q], P2.z, __fmaf_rn(qy[q], P2.y, __fmul_rn(qx[q], P2.x)))));
      float d3 = __fsub_rn(__fadd_rn(qw[q], P3.w), __fmul_rn(2.0f,
                 __fmaf_rn(qz[q], P3.z, __fmaf_rn(qy[q], P3.y, __fmul_rn(qx[q], P3.x)))));
      m[q] = fminf(fminf(fminf(m[q], d0), fminf(d1, d2)), d3);
    }
  }

  #pragma unroll
  for (int q = 0; q < 8; q++) cbuf[q][t] = m[q];
  __syncthreads();

  // ---- tau: wave w handles query w ----
  {
    // per-lane 3rd-smallest of its 8 thread-minima (bounds 3 real distances)
    float C0 = FLT_MAX, C1 = FLT_MAX, C2 = FLT_MAX;
    #pragma unroll
    for (int j = 0; j < 8; j++) {
      float v = cbuf[w][lane + 64*j];
      float n2 = __builtin_amdgcn_fmed3f(C1, C2, v);
      float n1 = __builtin_amdgcn_fmed3f(C0, C1, v);
      float n0 = fminf(C0, v);
      C0 = n0; C1 = n1; C2 = n2;
    }
    Lst[w][lane] = C2;
  }
  __syncthreads();
  {
    // tau = 6th-smallest L (rank 5, lex (L,lane) unique) -> >=18 pts <= tau
    float L = Lst[w][lane];
    int rk = 0;
    #pragma unroll 8
    for (int i = 0; i < 64; i++) {
      float Li = Lst[w][i];
      rk += (Li < L || (Li == L && i < lane)) ? 1 : 0;
    }
    if (rk == 5) tauS[w] = L;
  }
  __syncthreads();

  float tau[8];
  #pragma unroll
  for (int q = 0; q < 8; q++)
    tau[q] = __uint_as_float(__builtin_amdgcn_readfirstlane(__float_as_uint(tauS[q])));

  // ---- pass 2: re-stream points (L2-hot), predicate + collect ----
  for (int i0 = 0; i0 < 16; i0 += 4) {
    float4 Pb[4];
    Pb[0] = pb4[t + 512*(i0+0)];
    Pb[1] = pb4[t + 512*(i0+1)];
    Pb[2] = pb4[t + 512*(i0+2)];
    Pb[3] = pb4[t + 512*(i0+3)];
    #pragma unroll
    for (int u = 0; u < 4; u++) {
      float4 P = Pb[u];
      int idx = t + 512*(i0+u);
      #pragma unroll
      for (int q = 0; q < 8; q++) {
        float dot = __fmaf_rn(qz[q], P.z, __fmaf_rn(qy[q], P.y, __fmul_rn(qx[q], P.x)));
        float d2  = __fsub_rn(__fadd_rn(qw[q], P.w), __fmul_rn(2.0f, dot));
        if (d2 <= tau[q]) {
          int pos = atomicAdd(&ccnt[q], 1);
          if (pos < CCAP) {
            unsigned f = __float_as_uint(d2);
            unsigned mono = f ^ ((unsigned)((int)f >> 31) | 0x80000000u);
            coll[q][pos] = ((unsigned long long)mono << 32) | (unsigned)idx;
          }
        }
      }
    }
  }
  __syncthreads();

  // ---- extraction: exact rank via broadcast-compare (no serial chains) ----
  int cnt = __builtin_amdgcn_readfirstlane(ccnt[w]);
  if (cnt > CCAP) cnt = CCAP;
  unsigned long long k1 = (lane < cnt)      ? coll[w][lane]      : ~0ull;
  unsigned long long k2 = (lane + 64 < cnt) ? coll[w][lane + 64] : ~0ull;
  int r1 = 0, r2 = 0;
  for (int i = 0; i < cnt; i++) {
    unsigned long long ki = coll[w][i];   // broadcast read
    r1 += (ki < k1) ? 1 : 0;
    r2 += (ki < k2) ? 1 : 0;
  }

  int g = g0 + w;
  float4 Q = qS[w];
  if (lane < cnt && r1 >= 1 && r1 <= 16) {
    int om = (int)(k1 & 0xFFFFFFFFull);
    nb_idx[g*Kk + r1 - 1] = om;
    float4 Pm = pb4[om];
    p_out[(g*Kk + r1 - 1)*3 + 0] = __fsub_rn(Pm.x, Q.x);
    p_out[(g*Kk + r1 - 1)*3 + 1] = __fsub_rn(Pm.y, Q.y);
    p_out[(g*Kk + r1 - 1)*3 + 2] = __fsub_rn(Pm.z, Q.z);
  }
  if (lane + 64 < cnt && r2 >= 1 && r2 <= 16) {
    int om = (int)(k2 & 0xFFFFFFFFull);
    nb_idx[g*Kk + r2 - 1] = om;
    float4 Pm = pb4[om];
    p_out[(g*Kk + r2 - 1)*3 + 0] = __fsub_rn(Pm.x, Q.x);
    p_out[(g*Kk + r2 - 1)*3 + 1] = __fsub_rn(Pm.y, Q.y);
    p_out[(g*Kk + r2 - 1)*3 + 2] = __fsub_rn(Pm.z, Q.z);
  }
  if (lane < 3) rep_pos_out[g*3 + lane] = (lane == 0 ? Q.x : (lane == 1 ? Q.y : Q.z));
}

// ---------------- mlp v12: 512 thr / 8 waves / MG=8 — halved weight traffic AT occupancy ----------------
// v10/v11 post-mortem: the kernel wants BOTH halved weight traffic (v10's MG=8:
// 573->287 MB L2 stream) AND >=16 waves/CU (v11's MG=4 grid). v12 gets both:
// 512-thread blocks, 8 waves partition K (k === w mod 8), 8 groups share each
// weight fetch. Grid 512, LDS 43.3 KB -> 2-3 blk/CU = 16-24 waves/CU.
// Cross-wave reduce is two-phase RMW (waves 0-3 write red, barrier, waves 4-7
// += red, barrier) to keep red at 33.8 KB instead of 67.6. K regrouped 4->8
// chunks per output: FP regrouping only (threshold 0.14, current absmax 0.016).
// acc[8]/wb[4] statically indexed (v8 spill lesson); ~80 VGPR < 128 cap.
__device__ __forceinline__ void fma_g(float4& a, float hv, const float4& wv) {
  a.x = fmaf(hv, wv.x, a.x);
  a.y = fmaf(hv, wv.y, a.y);
  a.z = fmaf(hv, wv.z, a.z);
  a.w = fmaf(hv, wv.w, a.w);
}

__global__ __launch_bounds__(512) void mlp_kernel(
    const float* __restrict__ p,
    const float* __restrict__ t1t, const float* __restrict__ t1_b,
    const float* __restrict__ g1v, const float* __restrict__ b1v,
    const float* __restrict__ t2t, const float* __restrict__ t2_b,
    const float* __restrict__ g2v, const float* __restrict__ b2v,
    const float* __restrict__ t3t, const float* __restrict__ t3_b,
    const float* __restrict__ g3v, const float* __restrict__ b3v,
    float* __restrict__ T_out)
{
  __shared__ float pf[48][MGB];      // 1.5 KB
  __shared__ float hA[K2c][MGB];     // 8 KB
  __shared__ float red[128*66];      // 33.8 KB: row=(w4*4+comp)*8+q, col=l
  int t = threadIdx.x;
  int w = t >> 6, l = t & 63;
  int g0 = blockIdx.x * MGB;
  for (int e = t; e < MGB*48; e += 512) {
    int g = e / 48, k = e - g*48;
    pf[k][g] = p[(size_t)(g0+g)*48 + k];
  }
  __syncthreads();

  float4 acc[MGB];   // acc[q] = group q over cols 4l..4l+3
  int col = t & 255; // output neuron this thread reduces/writes
  int h   = t >> 8;  // group-half (0: q0..3, 1: q4..7)
  int cc  = col & 3, lr = col >> 2;

#define LDW(WSRC, K) (*(const float4*)&WSRC[(size_t)(K)*K2c + 4*l])

#define KSTAGE(WSRC, KDIM, HBUF, WB, KK, KNEXT)                        \
  {                                                                    \
    float4 wc = WB;                                                    \
    if ((KNEXT) < KDIM) WB = LDW(WSRC, KNEXT);                         \
    float4 ha = *(const float4*)&HBUF[KK][0];                          \
    float4 hb = *(const float4*)&HBUF[KK][4];                          \
    fma_g(acc[0], ha.x, wc); fma_g(acc[1], ha.y, wc);                  \
    fma_g(acc[2], ha.z, wc); fma_g(acc[3], ha.w, wc);                  \
    fma_g(acc[4], hb.x, wc); fma_g(acc[5], hb.y, wc);                  \
    fma_g(acc[6], hb.z, wc); fma_g(acc[7], hb.w, wc);                  \
  }

#define KLOOP(WSRC, KDIM, HBUF)                                        \
  {                                                                    \
    _Pragma("unroll")                                                  \
    for (int q = 0; q < MGB; q++) acc[q] = make_float4(0.f,0.f,0.f,0.f);\
    float4 wb0 = LDW(WSRC, w);                                         \
    float4 wb1 = (w + 8  < KDIM) ? LDW(WSRC, w + 8)  : wb0;            \
    float4 wb2 = (w + 16 < KDIM) ? LDW(WSRC, w + 16) : wb0;            \
    float4 wb3 = (w + 24 < KDIM) ? LDW(WSRC, w + 24) : wb0;            \
    for (int k = w; k < KDIM; k += 32) {                               \
      KSTAGE(WSRC, KDIM, HBUF, wb0, k,      k + 32)                    \
      if (k + 8  < KDIM) KSTAGE(WSRC, KDIM, HBUF, wb1, k + 8,  k + 40) \
      if (k + 16 < KDIM) KSTAGE(WSRC, KDIM, HBUF, wb2, k + 16, k + 48) \
      if (k + 24 < KDIM) KSTAGE(WSRC, KDIM, HBUF, wb3, k + 24, k + 56) \
    }                                                                  \
  }

// two-phase cross-wave reduce: waves 0-3 write rows, waves 4-7 accumulate
#define WRITE_RED()                                                    \
  {                                                                    \
    if (w < 4) {                                                       \
      _Pragma("unroll")                                                \
      for (int q = 0; q < MGB; q++) {                                  \
        red[((w*4 + 0)*8 + q)*66 + l] = acc[q].x;                      \
        red[((w*4 + 1)*8 + q)*66 + l] = acc[q].y;                      \
        red[((w*4 + 2)*8 + q)*66 + l] = acc[q].z;                      \
        red[((w*4 + 3)*8 + q)*66 + l] = acc[q].w;                      \
      }                                                                \
    }                                                                  \
    __syncthreads();                                                   \
    if (w >= 4) {                                                      \
      int w2 = w - 4;                                                  \
      _Pragma("unroll")                                                \
      for (int q = 0; q < MGB; q++) {                                  \
        red[((w2*4 + 0)*8 + q)*66 + l] += acc[q].x;                    \
        red[((w2*4 + 1)*8 + q)*66 + l] += acc[q].y;                    \
        red[((w2*4 + 2)*8 + q)*66 + l] += acc[q].z;                    \
        red[((w2*4 + 3)*8 + q)*66 + l] += acc[q].w;                    \
      }                                                                \
    }                                                                  \
    __syncthreads();                                                   \
  }

// thread t sums 4 ww-rows for its (col, group-half): S[qi] = out[col, h*4+qi]
#define REDUCE(S)                                                      \
  float S[4] = {0.f, 0.f, 0.f, 0.f};                                   \
  {                                                                    \
    _Pragma("unroll")                                                  \
    for (int ww = 0; ww < 4; ww++) {                                   \
      _Pragma("unroll")                                                \
      for (int qi = 0; qi < 4; qi++)                                   \
        S[qi] += red[((ww*4 + cc)*8 + (h*4 + qi))*66 + lr];            \
    }                                                                  \
  }

  // ===== layer 1 (K=48), relu =====
  KLOOP(t1t, 48, pf)
  WRITE_RED()
  {
    REDUCE(s)
    float bb = t1_b[col], gg = g1v[col], oo = b1v[col];
    float4 v;
    v.x = fmaxf(fmaf(s[0] + bb, gg, oo), 0.f);
    v.y = fmaxf(fmaf(s[1] + bb, gg, oo), 0.f);
    v.z = fmaxf(fmaf(s[2] + bb, gg, oo), 0.f);
    v.w = fmaxf(fmaf(s[3] + bb, gg, oo), 0.f);
    *(float4*)&hA[col][h*4] = v;
  }
  __syncthreads();

  // ===== layer 2 (K=256), relu =====
  KLOOP(t2t, K2c, hA)
  WRITE_RED()
  {
    REDUCE(s)
    float bb = t2_b[col], gg = g2v[col], oo = b2v[col];
    float4 v;
    v.x = fmaxf(fmaf(s[0] + bb, gg, oo), 0.f);
    v.y = fmaxf(fmaf(s[1] + bb, gg, oo), 0.f);
    v.z = fmaxf(fmaf(s[2] + bb, gg, oo), 0.f);
    v.w = fmaxf(fmaf(s[3] + bb, gg, oo), 0.f);
    *(float4*)&hA[col][h*4] = v;
  }
  __syncthreads();

  // ===== layer 3 (K=256), no relu, to global =====
  KLOOP(t3t, K2c, hA)
  WRITE_RED()
  {
    REDUCE(s)
    float bb = t3_b[col], gg = g3v[col], oo = b3v[col];
    #pragma unroll
    for (int qi = 0; qi < 4; qi++)
      T_out[(size_t)(g0 + h*4 + qi)*K2c + col] = fmaf(s[qi] + bb, gg, oo);
  }
#undef KLOOP
#undef KSTAGE
#undef LDW
#undef WRITE_RED
#undef REDUCE
}

// ---------------- tf (fused feat), 4 groups/block ----------------
__global__ __launch_bounds__(256) void tf_kernel(
    const float* __restrict__ T_in, const float* __restrict__ features,
    const float* __restrict__ p, const int* __restrict__ nb_idx,
    const float* __restrict__ lift_w, const float* __restrict__ lift_b,
    const float* __restrict__ bng, const float* __restrict__ bnb,
    float* __restrict__ Tf)
{
  __shared__ float T_s[4*K2c];    // 4 KB
  __shared__ float f_s[4*KC];     // 20 KB
  __shared__ float ps[4*48];      // 768 B
  __shared__ int   idxs[64];      // 256 B
  __shared__ float lw[48], lb2[16], lg[16], lo[16];
  int t = threadIdx.x;
  int g0 = blockIdx.x * 4;
  int b = g0 / Rr;                // 4 | 2048: block never straddles batches
  for (int e = t; e < 4*K2c; e += 256) T_s[e] = T_in[(size_t)g0*K2c + e];
  if (t >= 32 && t < 224) {
    int e = t - 32;               // 192 threads cover ps
    ps[e] = p[(size_t)g0*48 + e];
  }
  if (t < 64) idxs[t] = nb_idx[g0*16 + t];
  if (t >= 64 && t < 112)  lw[t-64]   = lift_w[t-64];
  if (t >= 112 && t < 128) lb2[t-112] = lift_b[t-112];
  if (t >= 224 && t < 240) lg[t-224]  = bng[t-224];
  if (t >= 240)            lo[t-240]  = bnb[t-240];
  __syncthreads();

  // gather neighbor features: 64 rows of 64
  {
    int wv = t >> 6, ln = t & 63;
    for (int row = wv; row < 64; row += 4) {
      int gg = row >> 4, k = row & 15;
      f_s[gg*KC + k*FD + CL + ln] = features[((size_t)b*Nn + idxs[row])*CIN + ln];
    }
  }
  // lifted BN+ReLU: 4*16*16 = 1024 elements
  for (int e = t; e < 1024; e += 256) {
    int gg = e >> 8, rem = e & 255, k = rem >> 4, c = rem & 15;
    float acc = ps[gg*48 + k*3 + 0]*lw[c*3+0] + ps[gg*48 + k*3 + 1]*lw[c*3+1]
              + ps[gg*48 + k*3 + 2]*lw[c*3+2] + lb2[c];
    acc = acc*lg[c] + lo[c];
    f_s[gg*KC + k*FD + c] = fmaxf(acc, 0.f);
  }
  __syncthreads();

  int gg = t >> 6;    // wave per group
  int cl = t & 63;
  for (int ci = cl; ci < FD; ci += 64) {
    float fcol[16];
    #pragma unroll
    for (int j = 0; j < 16; j++) fcol[j] = f_s[gg*KC + j*FD + ci];
    #pragma unroll
    for (int k = 0; k < 16; k++) {
      float acc = 0.f;
      #pragma unroll
      for (int j = 0; j < 16; j++) acc = fmaf(T_s[gg*K2c + k*16 + j], fcol[j], acc);
      Tf[(size_t)(g0+gg)*KC + k*FD + ci] = acc;
    }
  }
}

// ---------------- gemm: out = Tf(4096x1280) @ Wp(1280x128), split-K=4 ----------------
__global__ __launch_bounds__(256) void gemm_kernel(
    const float* __restrict__ A,    // Tf
    const float* __restrict__ Bm,   // Wp
    float* __restrict__ part)       // [SPLITK][GT][COUT]
{
  __shared__ float As[16*36];
  __shared__ float Bs[16*COUT];
  int t = threadIdx.x;
  int m0 = blockIdx.x * 32;
  int ky = blockIdx.y;
  int kbase0 = ky * (KC/SPLITK);    // 320
  float acc[4][4];
  #pragma unroll
  for (int i = 0; i < 4; i++)
    #pragma unroll
    for (int j = 0; j < 4; j++) acc[i][j] = 0.f;
  int tn = t & 31, tm = t >> 5;

  for (int kt = 0; kt < KC/SPLITK; kt += 16) {
    int kb = kbase0 + kt;
    {
      int kcol = t & 15, row = t >> 4;
      As[kcol*36 + row]      = A[(size_t)(m0+row)*KC + kb + kcol];
      As[kcol*36 + row + 16] = A[(size_t)(m0+row+16)*KC + kb + kcol];
    }
    {
      int o = t & 127, kk2 = t >> 7;
      #pragma unroll
      for (int p4 = 0; p4 < 8; p4++) {
        int kk = kk2 + p4*2;
        Bs[kk*COUT + o] = Bm[(size_t)(kb+kk)*COUT + o];
      }
    }
    __syncthreads();
    #pragma unroll
    for (int kk = 0; kk < 16; kk++) {
      float4 a4 = *(const float4*)&As[kk*36 + tm*4];
      float4 b4 = *(const float4*)&Bs[kk*COUT + tn*4];
      float av[4] = {a4.x, a4.y, a4.z, a4.w};
      float bv[4] = {b4.x, b4.y, b4.z, b4.w};
      #pragma unroll
      for (int i = 0; i < 4; i++)
        #pragma unroll
        for (int j = 0; j < 4; j++) acc[i][j] = fmaf(av[i], bv[j], acc[i][j]);
    }
    __syncthreads();
  }
  #pragma unroll
  for (int i = 0; i < 4; i++) {
    float4 v = make_float4(acc[i][0], acc[i][1], acc[i][2], acc[i][3]);
    *(float4*)&part[((size_t)ky*GT + m0 + tm*4 + i)*COUT + tn*4] = v;
  }
}

// ---------------- reduce: out = sum(part[0..SPLITK-1]) + bias ----------------
__global__ __launch_bounds__(256) void reduce_kernel(
    const float* __restrict__ part, const float* __restrict__ conv_b,
    float* __restrict__ outp)
{
  int i = blockIdx.x*256 + threadIdx.x;
  float4 s = ((const float4*)conv_b)[i & 31];
  #pragma unroll
  for (int w = 0; w < SPLITK; w++) {
    float4 v = ((const float4*)(part + (size_t)w*GT*COUT))[i];
    s.x += v.x; s.y += v.y; s.z += v.z; s.w += v.w;
  }
  ((float4*)outp)[i] = s;
}

extern "C" void kernel_launch(void* const* d_in, const int* in_sizes, int n_in,
                              void* d_out, int out_size, void* d_ws, size_t ws_size,
                              hipStream_t stream) {
  const float* points   = (const float*)d_in[0];
  const float* features = (const float*)d_in[1];
  const float* lift_w   = (const float*)d_in[2];
  const float* lift_b   = (const float*)d_in[3];
  const float* bn_lift_g= (const float*)d_in[4];
  const float* bn_lift_b= (const float*)d_in[5];
  const float* t1_w     = (const float*)d_in[6];
  const float* t1_b     = (const float*)d_in[7];
  const float* bn1_g    = (const float*)d_in[8];
  const float* bn1_b    = (const float*)d_in[9];
  const float* t2_w     = (const float*)d_in[10];
  const float* t2_b     = (const float*)d_in[11];
  const float* bn2_g    = (const float*)d_in[12];
  const float* bn2_b    = (const float*)d_in[13];
  const float* t3_w     = (const float*)d_in[14];
  const float* t3_b     = (const float*)d_in[15];
  const float* bn3_g    = (const float*)d_in[16];
  const float* bn3_b    = (const float*)d_in[17];
  const float* conv_w   = (const float*)d_in[18];
  const float* conv_b   = (const float*)d_in[19];
  const int*   rep_idx  = (const int*)d_in[20];

  char* ws = (char*)d_ws;
  int*    nb   = (int*)   (ws + 0);          // 256 KB
  float*  p    = (float*) (ws + 262144);     // 768 KB
  float*  T    = (float*) (ws + 1048576);    // 4 MB
  float*  Tf   = (float*) (ws + 5242880);    // 20 MB
  float*  wp   = (float*) (ws + 26214400);   // 640 KB
  float*  t1t  = (float*) (ws + 26869760);   // 48 KB
  float*  t2t  = (float*) (ws + 26918912);   // 256 KB
  float*  t3t  = (float*) (ws + 27181056);   // 256 KB
  float*  part = (float*) (ws + 33554432);   // 16 MB (SPLITK=4 uses 8 MB)
  float4* pts4 = (float4*)(ws + 52428800);   // 256 KB

  float* rep_pos = (float*)d_out;
  float* outp    = (float*)d_out + (size_t)GT*3;

  prep_kernel<<<640, 256, 0, stream>>>(t1_w, t2_w, t3_w, conv_w, points,
                                       t1t, t2t, t3t, wp, pts4);
  knn_kernel<<<GT/8, 512, 0, stream>>>(pts4, rep_idx, nb, p, rep_pos);
  mlp_kernel<<<GT/MGB, 512, 0, stream>>>(p, t1t, t1_b, bn1_g, bn1_b,
                                         t2t, t2_b, bn2_g, bn2_b,
                                         t3t, t3_b, bn3_g, bn3_b, T);
  tf_kernel<<<GT/4, 256, 0, stream>>>(T, features, p, nb,
                                      lift_w, lift_b, bn_lift_g, bn_lift_b, Tf);
  dim3 ggrid(GT/32, SPLITK);
  gemm_kernel<<<ggrid, 256, 0, stream>>>(Tf, wp, part);
  reduce_kernel<<<(GT*COUT/4)/256, 256, 0, stream>>>(part, conv_b, outp);
}

// Round 8
// 192.726 us; speedup vs baseline: 1.1217x; 1.0460x over previous
//
#include <hip/hip_runtime.h>
#include <float.h>

#define Bn 2
#define Nn 8192
#define Rr 2048
#define Kk 16
#define CIN 64
#define CL 16
#define COUT 128
#define K2c 256
#define GT (Bn*Rr)      // 4096 groups
#define FD (CL+CIN)     // 80
#define KC (Kk*FD)      // 1280
#define MGB 8           // mlp groups per block (8 groups, 8 waves, 512 thr)
#define SPLITK 4        // gemm split-K
#define CCAP 128        // knn candidate cap; expected count ~53 (v5.1 statistic)

// ---------------- prep: weight transposes / permute + pts4 packing ----------------
__global__ __launch_bounds__(256) void prep_kernel(
    const float* __restrict__ t1_w, const float* __restrict__ t2_w,
    const float* __restrict__ t3_w, const float* __restrict__ conv_w,
    const float* __restrict__ points,
    float* __restrict__ t1t, float* __restrict__ t2t,
    float* __restrict__ t3t, float* __restrict__ wp,
    float4* __restrict__ pts4)
{
  int i = blockIdx.x * 256 + threadIdx.x;
  if (i < K2c*48) { int j = i / 48, k = i - j*48; t1t[k*K2c + j] = t1_w[i]; }
  if (i < K2c*K2c) { int j = i >> 8, k = i & 255; t2t[k*K2c + j] = t2_w[i]; t3t[k*K2c + j] = t3_w[i]; }
  if (i < COUT*KC) {
    int o = i / KC, ck = i - o*KC;
    int c = ck >> 4, k = ck & 15;
    wp[(k*FD + c)*COUT + o] = conv_w[i];
  }
  if (i < Bn*Nn) {
    float x = points[i*3+0], y = points[i*3+1], z = points[i*3+2];
    // numpy order: sq = (x*x + y*y) + z*z, muls materialized then summed
    float sq = __fadd_rn(__fadd_rn(__fmul_rn(x,x), __fmul_rn(y,y)), __fmul_rn(z,z));
    pts4[i] = make_float4(x, y, z, sq);
  }
}

// ---------------- knn v9 (unchanged, harness-verified): streamed points ----------------
__global__ __launch_bounds__(512, 4) void knn_kernel(
    const float4* __restrict__ pts4, const int* __restrict__ rep_idx,
    int* __restrict__ nb_idx, float* __restrict__ p_out,
    float* __restrict__ rep_pos_out)
{
  __shared__ float cbuf[8][512];                 // 16 KB per-thread minima [q][t]
  __shared__ unsigned long long coll[8][CCAP];   // 8 KB candidates
  __shared__ float Lst[8][64];                   // 2 KB per-lane tau stats
  __shared__ float4 qS[8];
  __shared__ float  tauS[8];
  __shared__ int    ccnt[8];

  int t    = threadIdx.x;
  int lane = t & 63;
  int w    = t >> 6;                 // 0..7
  int g0   = blockIdx.x * 8;         // 8 | 2048: block never straddles batches
  int b    = g0 >> 11;
  const float4* pb4 = pts4 + (size_t)b*Nn;

  if (t < 8) {
    int g = g0 + t;
    int r = g & 2047;
    qS[t] = pb4[rep_idx[r]];
    ccnt[t] = 0;
  }
  __syncthreads();

  // queries to SGPRs (uniform across block)
  float qx[8], qy[8], qz[8], qw[8];
  #pragma unroll
  for (int q = 0; q < 8; q++) {
    float4 Q = qS[q];
    qx[q] = __uint_as_float(__builtin_amdgcn_readfirstlane(__float_as_uint(Q.x)));
    qy[q] = __uint_as_float(__builtin_amdgcn_readfirstlane(__float_as_uint(Q.y)));
    qz[q] = __uint_as_float(__builtin_amdgcn_readfirstlane(__float_as_uint(Q.z)));
    qw[q] = __uint_as_float(__builtin_amdgcn_readfirstlane(__float_as_uint(Q.w)));
  }

  // ---- pass 1: per-thread min d2 per query; points streamed 4-at-a-time ----
  float m[8];
  #pragma unroll
  for (int q = 0; q < 8; q++) m[q] = FLT_MAX;
  for (int i0 = 0; i0 < 16; i0 += 4) {
    float4 P0 = pb4[t + 512*(i0+0)];
    float4 P1 = pb4[t + 512*(i0+1)];
    float4 P2 = pb4[t + 512*(i0+2)];
    float4 P3 = pb4[t + 512*(i0+3)];
    #pragma unroll
    for (int q = 0; q < 8; q++) {
      float d0 = __fsub_rn(__fadd_rn(qw[q], P0.w), __fmul_rn(2.0f,
                 __fmaf_rn(qz[q], P0.z, __fmaf_rn(qy[q], P0.y, __fmul_rn(qx[q], P0.x)))));
      float d1 = __fsub_rn(__fadd_rn(qw[q], P1.w), __fmul_rn(2.0f,
                 __fmaf_rn(qz[q], P1.z, __fmaf_rn(qy[q], P1.y, __fmul_rn(qx[q], P1.x)))));
      float d2 = __fsub_rn(__fadd_rn(qw[q], P2.w), __fmul_rn(2.0f,
                 __fmaf_rn(qz[q], P2.z, __fmaf_rn(qy[q], P2.y, __fmul_rn(qx[q], P2.x)))));
      float d3 = __fsub_rn(__fadd_rn(qw[q], P3.w), __fmul_rn(2.0f,
                 __fmaf_rn(qz[q], P3.z, __fmaf_rn(qy[q], P3.y, __fmul_rn(qx[q], P3.x)))));
      m[q] = fminf(fminf(fminf(m[q], d0), fminf(d1, d2)), d3);
    }
  }

  #pragma unroll
  for (int q = 0; q < 8; q++) cbuf[q][t] = m[q];
  __syncthreads();

  // ---- tau: wave w handles query w ----
  {
    // per-lane 3rd-smallest of its 8 thread-minima (bounds 3 real distances)
    float C0 = FLT_MAX, C1 = FLT_MAX, C2 = FLT_MAX;
    #pragma unroll
    for (int j = 0; j < 8; j++) {
      float v = cbuf[w][lane + 64*j];
      float n2 = __builtin_amdgcn_fmed3f(C1, C2, v);
      float n1 = __builtin_amdgcn_fmed3f(C0, C1, v);
      float n0 = fminf(C0, v);
      C0 = n0; C1 = n1; C2 = n2;
    }
    Lst[w][lane] = C2;
  }
  __syncthreads();
  {
    // tau = 6th-smallest L (rank 5, lex (L,lane) unique) -> >=18 pts <= tau
    float L = Lst[w][lane];
    int rk = 0;
    #pragma unroll 8
    for (int i = 0; i < 64; i++) {
      float Li = Lst[w][i];
      rk += (Li < L || (Li == L && i < lane)) ? 1 : 0;
    }
    if (rk == 5) tauS[w] = L;
  }
  __syncthreads();

  float tau[8];
  #pragma unroll
  for (int q = 0; q < 8; q++)
    tau[q] = __uint_as_float(__builtin_amdgcn_readfirstlane(__float_as_uint(tauS[q])));

  // ---- pass 2: re-stream points (L2-hot), predicate + collect ----
  for (int i0 = 0; i0 < 16; i0 += 4) {
    float4 Pb[4];
    Pb[0] = pb4[t + 512*(i0+0)];
    Pb[1] = pb4[t + 512*(i0+1)];
    Pb[2] = pb4[t + 512*(i0+2)];
    Pb[3] = pb4[t + 512*(i0+3)];
    #pragma unroll
    for (int u = 0; u < 4; u++) {
      float4 P = Pb[u];
      int idx = t + 512*(i0+u);
      #pragma unroll
      for (int q = 0; q < 8; q++) {
        float dot = __fmaf_rn(qz[q], P.z, __fmaf_rn(qy[q], P.y, __fmul_rn(qx[q], P.x)));
        float d2  = __fsub_rn(__fadd_rn(qw[q], P.w), __fmul_rn(2.0f, dot));
        if (d2 <= tau[q]) {
          int pos = atomicAdd(&ccnt[q], 1);
          if (pos < CCAP) {
            unsigned f = __float_as_uint(d2);
            unsigned mono = f ^ ((unsigned)((int)f >> 31) | 0x80000000u);
            coll[q][pos] = ((unsigned long long)mono << 32) | (unsigned)idx;
          }
        }
      }
    }
  }
  __syncthreads();

  // ---- extraction: exact rank via broadcast-compare (no serial chains) ----
  int cnt = __builtin_amdgcn_readfirstlane(ccnt[w]);
  if (cnt > CCAP) cnt = CCAP;
  unsigned long long k1 = (lane < cnt)      ? coll[w][lane]      : ~0ull;
  unsigned long long k2 = (lane + 64 < cnt) ? coll[w][lane + 64] : ~0ull;
  int r1 = 0, r2 = 0;
  for (int i = 0; i < cnt; i++) {
    unsigned long long ki = coll[w][i];   // broadcast read
    r1 += (ki < k1) ? 1 : 0;
    r2 += (ki < k2) ? 1 : 0;
  }

  int g = g0 + w;
  float4 Q = qS[w];
  if (lane < cnt && r1 >= 1 && r1 <= 16) {
    int om = (int)(k1 & 0xFFFFFFFFull);
    nb_idx[g*Kk + r1 - 1] = om;
    float4 Pm = pb4[om];
    p_out[(g*Kk + r1 - 1)*3 + 0] = __fsub_rn(Pm.x, Q.x);
    p_out[(g*Kk + r1 - 1)*3 + 1] = __fsub_rn(Pm.y, Q.y);
    p_out[(g*Kk + r1 - 1)*3 + 2] = __fsub_rn(Pm.z, Q.z);
  }
  if (lane + 64 < cnt && r2 >= 1 && r2 <= 16) {
    int om = (int)(k2 & 0xFFFFFFFFull);
    nb_idx[g*Kk + r2 - 1] = om;
    float4 Pm = pb4[om];
    p_out[(g*Kk + r2 - 1)*3 + 0] = __fsub_rn(Pm.x, Q.x);
    p_out[(g*Kk + r2 - 1)*3 + 1] = __fsub_rn(Pm.y, Q.y);
    p_out[(g*Kk + r2 - 1)*3 + 2] = __fsub_rn(Pm.z, Q.z);
  }
  if (lane < 3) rep_pos_out[g*3 + lane] = (lane == 0 ? Q.x : (lane == 1 ? Q.y : Q.z));
}

// ---------------- mlp_tf v13: v12 mlp + fused tf phase (T never leaves LDS) ----------------
// Accounting (R7): per-kernel floors leave a large gap to the 201.6us total ->
// launch/drain overhead + intermediate round-trips are the sink. The mlp block
// computes T for exactly the 8 groups tf consumes: fuse. After layer 3, T is
// written to LDS (reusing hA, dead after the last KLOOP); the tf phase (gather
// neighbor features -> lift BN+ReLU -> T x feat) runs in-block, reusing red
// (dead after last REDUCE) as f_s, 4 groups/pass x 2 passes. Eliminates the tf
// launch + device drain + the 4MB T buffer (8MB traffic). FP preserved: T
// values bit-identical fmaf; tf matmul keeps exact j-ascending fma order; lift
// expression verbatim. LDS ~44.4KB -> 3 blocks/CU.
__device__ __forceinline__ void fma_g(float4& a, float hv, const float4& wv) {
  a.x = fmaf(hv, wv.x, a.x);
  a.y = fmaf(hv, wv.y, a.y);
  a.z = fmaf(hv, wv.z, a.z);
  a.w = fmaf(hv, wv.w, a.w);
}

__global__ __launch_bounds__(512) void mlp_tf_kernel(
    const float* __restrict__ p,
    const float* __restrict__ t1t, const float* __restrict__ t1_b,
    const float* __restrict__ g1v, const float* __restrict__ b1v,
    const float* __restrict__ t2t, const float* __restrict__ t2_b,
    const float* __restrict__ g2v, const float* __restrict__ b2v,
    const float* __restrict__ t3t, const float* __restrict__ t3_b,
    const float* __restrict__ g3v, const float* __restrict__ b3v,
    const float* __restrict__ features, const int* __restrict__ nb_idx,
    const float* __restrict__ lift_w, const float* __restrict__ lift_b,
    const float* __restrict__ bng, const float* __restrict__ bnb,
    float* __restrict__ Tf)
{
  __shared__ float pf[48][MGB];      // 1.5 KB (= p transposed; also serves tf lift)
  __shared__ float hA[K2c][MGB];     // 8 KB (layer I/O; reused as T_s after layer 3)
  __shared__ float red[128*66];      // 33.8 KB (reduction; reused as f_s in tf phase)
  __shared__ int   idxs[128];        // 512 B (8 groups x 16 neighbors)
  __shared__ float lw[48], lb2[16], lg[16], lo[16];
  int t = threadIdx.x;
  int w = t >> 6, l = t & 63;
  int g0 = blockIdx.x * MGB;
  int bb_ = g0 / Rr;                 // batch (8 | 2048: never straddles)
  for (int e = t; e < MGB*48; e += 512) {
    int g = e / 48, k = e - g*48;
    pf[k][g] = p[(size_t)(g0+g)*48 + k];
  }
  if (t < 128) idxs[t] = nb_idx[g0*16 + t];
  else if (t >= 128 && t < 176) lw[t-128]  = lift_w[t-128];
  else if (t >= 176 && t < 192) lb2[t-176] = lift_b[t-176];
  else if (t >= 192 && t < 208) lg[t-192]  = bng[t-192];
  else if (t >= 208 && t < 224) lo[t-208]  = bnb[t-208];
  __syncthreads();

  float4 acc[MGB];   // acc[q] = group q over cols 4l..4l+3
  int col = t & 255; // output neuron this thread reduces/writes
  int h   = t >> 8;  // group-half (0: q0..3, 1: q4..7)
  int cc  = col & 3, lr = col >> 2;

#define LDW(WSRC, K) (*(const float4*)&WSRC[(size_t)(K)*K2c + 4*l])

#define KSTAGE(WSRC, KDIM, HBUF, WB, KK, KNEXT)                        \
  {                                                                    \
    float4 wc = WB;                                                    \
    if ((KNEXT) < KDIM) WB = LDW(WSRC, KNEXT);                         \
    float4 ha = *(const float4*)&HBUF[KK][0];                          \
    float4 hb = *(const float4*)&HBUF[KK][4];                          \
    fma_g(acc[0], ha.x, wc); fma_g(acc[1], ha.y, wc);                  \
    fma_g(acc[2], ha.z, wc); fma_g(acc[3], ha.w, wc);                  \
    fma_g(acc[4], hb.x, wc); fma_g(acc[5], hb.y, wc);                  \
    fma_g(acc[6], hb.z, wc); fma_g(acc[7], hb.w, wc);                  \
  }

#define KLOOP(WSRC, KDIM, HBUF)                                        \
  {                                                                    \
    _Pragma("unroll")                                                  \
    for (int q = 0; q < MGB; q++) acc[q] = make_float4(0.f,0.f,0.f,0.f);\
    float4 wb0 = LDW(WSRC, w);                                         \
    float4 wb1 = (w + 8  < KDIM) ? LDW(WSRC, w + 8)  : wb0;            \
    float4 wb2 = (w + 16 < KDIM) ? LDW(WSRC, w + 16) : wb0;            \
    float4 wb3 = (w + 24 < KDIM) ? LDW(WSRC, w + 24) : wb0;            \
    for (int k = w; k < KDIM; k += 32) {                               \
      KSTAGE(WSRC, KDIM, HBUF, wb0, k,      k + 32)                    \
      if (k + 8  < KDIM) KSTAGE(WSRC, KDIM, HBUF, wb1, k + 8,  k + 40) \
      if (k + 16 < KDIM) KSTAGE(WSRC, KDIM, HBUF, wb2, k + 16, k + 48) \
      if (k + 24 < KDIM) KSTAGE(WSRC, KDIM, HBUF, wb3, k + 24, k + 56) \
    }                                                                  \
  }

// two-phase cross-wave reduce: waves 0-3 write rows, waves 4-7 accumulate
#define WRITE_RED()                                                    \
  {                                                                    \
    if (w < 4) {                                                       \
      _Pragma("unroll")                                                \
      for (int q = 0; q < MGB; q++) {                                  \
        red[((w*4 + 0)*8 + q)*66 + l] = acc[q].x;                      \
        red[((w*4 + 1)*8 + q)*66 + l] = acc[q].y;                      \
        red[((w*4 + 2)*8 + q)*66 + l] = acc[q].z;                      \
        red[((w*4 + 3)*8 + q)*66 + l] = acc[q].w;                      \
      }                                                                \
    }                                                                  \
    __syncthreads();                                                   \
    if (w >= 4) {                                                      \
      int w2 = w - 4;                                                  \
      _Pragma("unroll")                                                \
      for (int q = 0; q < MGB; q++) {                                  \
        red[((w2*4 + 0)*8 + q)*66 + l] += acc[q].x;                    \
        red[((w2*4 + 1)*8 + q)*66 + l] += acc[q].y;                    \
        red[((w2*4 + 2)*8 + q)*66 + l] += acc[q].z;                    \
        red[((w2*4 + 3)*8 + q)*66 + l] += acc[q].w;                    \
      }                                                                \
    }                                                                  \
    __syncthreads();                                                   \
  }

// thread t sums 4 ww-rows for its (col, group-half): S[qi] = out[col, h*4+qi]
#define REDUCE(S)                                                      \
  float S[4] = {0.f, 0.f, 0.f, 0.f};                                   \
  {                                                                    \
    _Pragma("unroll")                                                  \
    for (int ww = 0; ww < 4; ww++) {                                   \
      _Pragma("unroll")                                                \
      for (int qi = 0; qi < 4; qi++)                                   \
        S[qi] += red[((ww*4 + cc)*8 + (h*4 + qi))*66 + lr];            \
    }                                                                  \
  }

  // ===== layer 1 (K=48), relu =====
  KLOOP(t1t, 48, pf)
  WRITE_RED()
  {
    REDUCE(s)
    float bb = t1_b[col], gg = g1v[col], oo = b1v[col];
    float4 v;
    v.x = fmaxf(fmaf(s[0] + bb, gg, oo), 0.f);
    v.y = fmaxf(fmaf(s[1] + bb, gg, oo), 0.f);
    v.z = fmaxf(fmaf(s[2] + bb, gg, oo), 0.f);
    v.w = fmaxf(fmaf(s[3] + bb, gg, oo), 0.f);
    *(float4*)&hA[col][h*4] = v;
  }
  __syncthreads();

  // ===== layer 2 (K=256), relu =====
  KLOOP(t2t, K2c, hA)
  WRITE_RED()
  {
    REDUCE(s)
    float bb = t2_b[col], gg = g2v[col], oo = b2v[col];
    float4 v;
    v.x = fmaxf(fmaf(s[0] + bb, gg, oo), 0.f);
    v.y = fmaxf(fmaf(s[1] + bb, gg, oo), 0.f);
    v.z = fmaxf(fmaf(s[2] + bb, gg, oo), 0.f);
    v.w = fmaxf(fmaf(s[3] + bb, gg, oo), 0.f);
    *(float4*)&hA[col][h*4] = v;
  }
  __syncthreads();

  // ===== layer 3 (K=256), no relu, T -> LDS (hA reused as T_s) =====
  KLOOP(t3t, K2c, hA)
  WRITE_RED()
  float* T_s = &hA[0][0];   // T_s[g*256 + col]; hA dead after last KLOOP
  {
    REDUCE(s)
    float bb = t3_b[col], gg = g3v[col], oo = b3v[col];
    #pragma unroll
    for (int qi = 0; qi < 4; qi++)
      T_s[(h*4 + qi)*K2c + col] = fmaf(s[qi] + bb, gg, oo);
  }
  __syncthreads();          // red reads done (f_s reuse safe), T_s visible

  // ===== tf phase: 4 groups per pass, 2 passes (f_s reuses red) =====
  float* f_s = red;         // f_s[gg4*KC + k*FD + c], 4*1280 floats = 20 KB
  for (int pass = 0; pass < 2; pass++) {
    // gather neighbor features: 64 rows (4 groups x 16 nbrs) x 64 ch
    for (int row = w; row < 64; row += 8) {
      int gg4 = row >> 4, k = row & 15;
      int gl = pass*4 + gg4;
      f_s[gg4*KC + k*FD + CL + l] =
          features[((size_t)bb_*Nn + idxs[gl*16 + k])*CIN + l];
    }
    // lifted BN+ReLU: 4*16*16 = 1024 elements
    for (int e = t; e < 1024; e += 512) {
      int gg4 = e >> 8, rem = e & 255, k = rem >> 4, c = rem & 15;
      int gl = pass*4 + gg4;
      float a = pf[k*3 + 0][gl]*lw[c*3+0] + pf[k*3 + 1][gl]*lw[c*3+1]
              + pf[k*3 + 2][gl]*lw[c*3+2] + lb2[c];
      a = a*lg[c] + lo[c];
      f_s[gg4*KC + k*FD + c] = fmaxf(a, 0.f);
    }
    __syncthreads();
    // T x feat: 2 waves per group (ci = sub*64 + lane)
    {
      int gg4 = w >> 1, sub = w & 1;
      int ci = sub*64 + l;
      if (ci < FD) {
        int gl = pass*4 + gg4;
        float fcol[16];
        #pragma unroll
        for (int j = 0; j < 16; j++) fcol[j] = f_s[gg4*KC + j*FD + ci];
        #pragma unroll
        for (int k = 0; k < 16; k++) {
          float a = 0.f;
          #pragma unroll
          for (int j = 0; j < 16; j++)
            a = fmaf(T_s[gl*K2c + k*16 + j], fcol[j], a);
          Tf[(size_t)(g0+gl)*KC + k*FD + ci] = a;
        }
      }
    }
    __syncthreads();        // f_s reads done before next pass overwrite
  }
#undef KLOOP
#undef KSTAGE
#undef LDW
#undef WRITE_RED
#undef REDUCE
}

// ---------------- gemm: out = Tf(4096x1280) @ Wp(1280x128), split-K=4 ----------------
__global__ __launch_bounds__(256) void gemm_kernel(
    const float* __restrict__ A,    // Tf
    const float* __restrict__ Bm,   // Wp
    float* __restrict__ part)       // [SPLITK][GT][COUT]
{
  __shared__ float As[16*36];
  __shared__ float Bs[16*COUT];
  int t = threadIdx.x;
  int m0 = blockIdx.x * 32;
  int ky = blockIdx.y;
  int kbase0 = ky * (KC/SPLITK);    // 320
  float acc[4][4];
  #pragma unroll
  for (int i = 0; i < 4; i++)
    #pragma unroll
    for (int j = 0; j < 4; j++) acc[i][j] = 0.f;
  int tn = t & 31, tm = t >> 5;

  for (int kt = 0; kt < KC/SPLITK; kt += 16) {
    int kb = kbase0 + kt;
    {
      int kcol = t & 15, row = t >> 4;
      As[kcol*36 + row]      = A[(size_t)(m0+row)*KC + kb + kcol];
      As[kcol*36 + row + 16] = A[(size_t)(m0+row+16)*KC + kb + kcol];
    }
    {
      int o = t & 127, kk2 = t >> 7;
      #pragma unroll
      for (int p4 = 0; p4 < 8; p4++) {
        int kk = kk2 + p4*2;
        Bs[kk*COUT + o] = Bm[(size_t)(kb+kk)*COUT + o];
      }
    }
    __syncthreads();
    #pragma unroll
    for (int kk = 0; kk < 16; kk++) {
      float4 a4 = *(const float4*)&As[kk*36 + tm*4];
      float4 b4 = *(const float4*)&Bs[kk*COUT + tn*4];
      float av[4] = {a4.x, a4.y, a4.z, a4.w};
      float bv[4] = {b4.x, b4.y, b4.z, b4.w};
      #pragma unroll
      for (int i = 0; i < 4; i++)
        #pragma unroll
        for (int j = 0; j < 4; j++) acc[i][j] = fmaf(av[i], bv[j], acc[i][j]);
    }
    __syncthreads();
  }
  #pragma unroll
  for (int i = 0; i < 4; i++) {
    float4 v = make_float4(acc[i][0], acc[i][1], acc[i][2], acc[i][3]);
    *(float4*)&part[((size_t)ky*GT + m0 + tm*4 + i)*COUT + tn*4] = v;
  }
}

// ---------------- reduce: out = sum(part[0..SPLITK-1]) + bias ----------------
__global__ __launch_bounds__(256) void reduce_kernel(
    const float* __restrict__ part, const float* __restrict__ conv_b,
    float* __restrict__ outp)
{
  int i = blockIdx.x*256 + threadIdx.x;
  float4 s = ((const float4*)conv_b)[i & 31];
  #pragma unroll
  for (int w = 0; w < SPLITK; w++) {
    float4 v = ((const float4*)(part + (size_t)w*GT*COUT))[i];
    s.x += v.x; s.y += v.y; s.z += v.z; s.w += v.w;
  }
  ((float4*)outp)[i] = s;
}

extern "C" void kernel_launch(void* const* d_in, const int* in_sizes, int n_in,
                              void* d_out, int out_size, void* d_ws, size_t ws_size,
                              hipStream_t stream) {
  const float* points   = (const float*)d_in[0];
  const float* features = (const float*)d_in[1];
  const float* lift_w   = (const float*)d_in[2];
  const float* lift_b   = (const float*)d_in[3];
  const float* bn_lift_g= (const float*)d_in[4];
  const float* bn_lift_b= (const float*)d_in[5];
  const float* t1_w     = (const float*)d_in[6];
  const float* t1_b     = (const float*)d_in[7];
  const float* bn1_g    = (const float*)d_in[8];
  const float* bn1_b    = (const float*)d_in[9];
  const float* t2_w     = (const float*)d_in[10];
  const float* t2_b     = (const float*)d_in[11];
  const float* bn2_g    = (const float*)d_in[12];
  const float* bn2_b    = (const float*)d_in[13];
  const float* t3_w     = (const float*)d_in[14];
  const float* t3_b     = (const float*)d_in[15];
  const float* bn3_g    = (const float*)d_in[16];
  const float* bn3_b    = (const float*)d_in[17];
  const float* conv_w   = (const float*)d_in[18];
  const float* conv_b   = (const float*)d_in[19];
  const int*   rep_idx  = (const int*)d_in[20];

  char* ws = (char*)d_ws;
  int*    nb   = (int*)   (ws + 0);          // 256 KB
  float*  p    = (float*) (ws + 262144);     // 768 KB
  float*  Tf   = (float*) (ws + 5242880);    // 20 MB
  float*  wp   = (float*) (ws + 26214400);   // 640 KB
  float*  t1t  = (float*) (ws + 26869760);   // 48 KB
  float*  t2t  = (float*) (ws + 26918912);   // 256 KB
  float*  t3t  = (float*) (ws + 27181056);   // 256 KB
  float*  part = (float*) (ws + 33554432);   // 8 MB (SPLITK=4)
  float4* pts4 = (float4*)(ws + 52428800);   // 256 KB

  float* rep_pos = (float*)d_out;
  float* outp    = (float*)d_out + (size_t)GT*3;

  prep_kernel<<<640, 256, 0, stream>>>(t1_w, t2_w, t3_w, conv_w, points,
                                       t1t, t2t, t3t, wp, pts4);
  knn_kernel<<<GT/8, 512, 0, stream>>>(pts4, rep_idx, nb, p, rep_pos);
  mlp_tf_kernel<<<GT/MGB, 512, 0, stream>>>(p, t1t, t1_b, bn1_g, bn1_b,
                                            t2t, t2_b, bn2_g, bn2_b,
                                            t3t, t3_b, bn3_g, bn3_b,
                                            features, nb,
                                            lift_w, lift_b, bn_lift_g, bn_lift_b,
                                            Tf);
  dim3 ggrid(GT/32, SPLITK);
  gemm_kernel<<<ggrid, 256, 0, stream>>>(Tf, wp, part);
  reduce_kernel<<<(GT*COUT/4)/256, 256, 0, stream>>>(part, conv_b, outp);
}